// Round 6
// baseline (693.363 us; speedup 1.0000x reference)
//
#include <hip/hip_runtime.h>
#include <hip/hip_bf16.h>

typedef __hip_bfloat16 bf16;
typedef __attribute__((ext_vector_type(8))) short short8;
typedef __attribute__((ext_vector_type(4))) float f32x4;

#define DEV __device__ __forceinline__
DEV float b2f(bf16 v){ return __bfloat162float(v); }
DEV bf16 f2b(float v){ return __float2bfloat16(v); }
DEV short f2bs(float v){ union{ bf16 b; short s; } u; u.b = __float2bfloat16(v); return u.s; }
DEV float s2f(short s){ union{ short s; bf16 b; } u; u.s = s; return __bfloat162float(u.b); }
DEV float sigm(float x){ return 1.f/(1.f + expf(-x)); }

// ---- problem constants ----
#define BB 4
#define CIN 256
#define MID 128
#define COUT 64
#define HH 128
#define WW 128
#define WS 8
#define HEADS 8
#define HD 16
#define NTOK 64
#define NWIN 1024

// LDS slot swizzle: row-major 64B rows, slot = cq ^ ((row>>1)&3)
#define SLOT(row,cq) ((cq) ^ (((row)>>1)&3))

// ---- workspace layout (bytes) ----
static const size_t OFF_H     = 0;
static const size_t OFF_LOCAL = 33554432;
static const size_t OFF_Q     = 67108864;
static const size_t OFF_K     = 83886080;
static const size_t OFF_V     = 100663296;
static const size_t OFF_DOTS  = 117440512;
static const size_t OFF_Z1    = 184549376;
static const size_t OFF_Z2    = 186646528;
static const size_t OFF_Z3    = 188743680;
static const size_t OFF_G1    = 205520896;
static const size_t OFF_G2    = 207618048;
static const size_t OFF_G3    = 209715200;
static const size_t OFF_HT    = OFF_DOTS + 34078720;

// ============ P1: repack conv_w -> w2[kk][co][ci] bf16 ============
__global__ __launch_bounds__(256) void k_wrep(const float* __restrict__ w, short* __restrict__ w2){
  int i = blockIdx.x*256 + threadIdx.x;
  int ci = i & 255, co = (i >> 8) & 127, kk = i >> 15;
  w2[i] = f2bs(w[(co*256 + ci)*9 + kk]);
}

// ============ P2: zero pad columns of xT ============
__global__ void k_xzero(short* __restrict__ xT){
  int t = blockIdx.x*256 + threadIdx.x;
  int ci = t & 255, side = (t >> 8) & 1, row = t >> 9;
  int cpad = side ? 129 : 0;
  xT[((size_t)row*130 + cpad)*256 + ci] = 0;
}

// ============ P3: x NCHW fp32 -> xT[b][r][c+1][ci] bf16 ============
__global__ __launch_bounds__(256) void k_xrep(const float* __restrict__ x, short* __restrict__ xT){
  const int blk = blockIdx.x;
  const int cgrp = blk & 1, cig = (blk >> 1) & 7, r = (blk >> 4) & 127, b = blk >> 11;
  const int c0 = cgrp*64, ci0 = cig*32;
  __shared__ float lds[32][65];
  const int t = threadIdx.x;
  for (int i = t; i < 2048; i += 256){
    int lci = i >> 6, c = i & 63;
    lds[lci][c] = x[((size_t)(b*256 + ci0 + lci)*128 + r)*128 + c0 + c];
  }
  __syncthreads();
  for (int i = t; i < 2048; i += 256){
    int lci = i & 31, cc = i >> 5;
    xT[((size_t)(b*128 + r)*130 + c0 + cc + 1)*256 + ci0 + lci] = f2bs(lds[lci][cc]);
  }
}

// ============ K1: conv3x3 256->128 + bn + relu -> hT bf16 ============
// R3 geometry (2-row blocks, grid 512) + register-prefetch (issue-early/write-late).
__global__ __launch_bounds__(256) void k_conv1m(const short* __restrict__ xT, const short* __restrict__ w2,
      const float* __restrict__ gg, const float* __restrict__ bb, short* __restrict__ hT){
  int blk = blockIdx.x;
  blk = (blk & 7)*64 + (blk >> 3);          // XCD swizzle (grid 512)
  const int cg = blk & 1, y2 = (blk >> 1) & 63, b = blk >> 7;
  const int t = threadIdx.x, lane = t & 63, wave = t >> 6;
  const int quad = lane >> 4, l15 = lane & 15;
  const int r = wave >> 1, x0w = (wave & 1)*64;
  __shared__ __align__(16) short smem[22784];   // A 4*130*32 + B 192*32
  short* as = smem;            // ((sr*130+col)*4 + SLOT(col,cq))*8
  short* bs = smem + 16640;    // (rr*4 + SLOT(rr,cq))*8, rr = kx*64+co_l
  uint4 areg[9], breg[3];
  f32x4 acc[4][4];
  #pragma unroll
  for (int i = 0; i < 4; ++i)
    #pragma unroll
    for (int j = 0; j < 4; ++j) acc[i][j] = (f32x4){0.f,0.f,0.f,0.f};

  auto loadA = [&](int ch){
    const int ci0 = ch*32;
    #pragma unroll
    for (int j = 0; j < 9; ++j){
      int i = t + j*256;
      uint4 val = {0,0,0,0};
      if (i < 2080){
        int sr = i / 520, jj = i - sr*520;
        int col = jj >> 2, cq = jj & 3;
        int g = 2*y2 - 1 + sr;
        if ((unsigned)g < 128u)
          val = *(const uint4*)&xT[((size_t)(b*128+g)*130 + col)*256 + ci0 + cq*8];
      }
      areg[j] = val;
    }
  };
  auto writeA = [&](){
    #pragma unroll
    for (int j = 0; j < 9; ++j){
      int i = t + j*256;
      if (i < 2080){
        int sr = i / 520, jj = i - sr*520;
        int col = jj >> 2, cq = jj & 3;
        *(uint4*)&as[((sr*130 + col)*4 + SLOT(col,cq))*8] = areg[j];
      }
    }
  };
  auto loadB = [&](int ch, int ky){
    const int ci0 = ch*32;
    #pragma unroll
    for (int j = 0; j < 3; ++j){
      int i = t + j*256;
      int rr = i >> 2, cq = i & 3;
      int kk = ky*3 + (rr >> 6), co_l = rr & 63;
      breg[j] = *(const uint4*)&w2[((size_t)(kk*128 + cg*64 + co_l))*256 + ci0 + cq*8];
    }
  };
  auto writeB = [&](){
    #pragma unroll
    for (int j = 0; j < 3; ++j){
      int i = t + j*256;
      int rr = i >> 2, cq = i & 3;
      *(uint4*)&bs[(rr*4 + SLOT(rr,cq))*8] = breg[j];
    }
  };
  auto compute = [&](int sr){
    #pragma unroll
    for (int kx = 0; kx < 3; ++kx){
      short8 af[4], bf[4];
      #pragma unroll
      for (int mt = 0; mt < 4; ++mt){
        int col = x0w + mt*16 + l15 + kx;
        af[mt] = *(const short8*)&as[((sr*130 + col)*4 + SLOT(col,quad))*8];
      }
      #pragma unroll
      for (int nt = 0; nt < 4; ++nt){
        int rr = kx*64 + nt*16 + l15;
        bf[nt] = *(const short8*)&bs[(rr*4 + SLOT(rr,quad))*8];
      }
      #pragma unroll
      for (int mt = 0; mt < 4; ++mt)
        #pragma unroll
        for (int nt = 0; nt < 4; ++nt)
          acc[mt][nt] = __builtin_amdgcn_mfma_f32_16x16x32_bf16(af[mt], bf[nt], acc[mt][nt], 0, 0, 0);
    }
  };

  loadA(0); loadB(0, 0);
  #pragma unroll 1
  for (int ch = 0; ch < 8; ++ch){
    #pragma unroll 1
    for (int ky = 0; ky < 3; ++ky){
      __syncthreads();
      if (ky == 0) writeA();
      writeB();
      if (ky < 2) loadB(ch, ky+1);
      else if (ch < 7){ loadA(ch+1); loadB(ch+1, 0); }
      __syncthreads();
      compute(r + ky);
    }
  }
  // epilogue: bn+relu, transpose via LDS, write bf16 NHWC rows of hT
  __syncthreads();
  short* tb = smem;   // [2][128][72]
  #pragma unroll
  for (int nt = 0; nt < 4; ++nt){
    int cl = nt*16 + l15, co = cg*64 + cl;
    float g = gg[co], bia = bb[co];
    #pragma unroll
    for (int mt = 0; mt < 4; ++mt){
      int xb = x0w + mt*16 + quad*4;
      #pragma unroll
      for (int r2 = 0; r2 < 4; ++r2)
        tb[(r*128 + xb + r2)*72 + cl] = f2bs(fmaxf(acc[mt][nt][r2]*g + bia, 0.f));
    }
  }
  __syncthreads();
  for (int i = t; i < 2048; i += 256){
    int rr = i >> 10, xx = (i >> 3) & 127, c8 = i & 7;
    *(uint4*)&hT[((size_t)(b*128 + 2*y2 + rr)*130 + xx + 1)*128 + cg*64 + c8*8] =
      *(const uint4*)&tb[(rr*128 + xx)*72 + c8*8];
  }
}

// ============ P4: zero pad columns of hT ============
__global__ void k_hzero(short* __restrict__ hT){
  int t = blockIdx.x*256 + threadIdx.x;
  int ci = t & 127, side = (t >> 7) & 1, row = t >> 8;
  int cpad = side ? 129 : 0;
  hT[((size_t)row*130 + cpad)*128 + ci] = 0;
}

// ============ P6: fold local weights: wloc[kk][co][ci] bf16 ============
__global__ __launch_bounds__(256) void k_lwrep(const float* __restrict__ w1, const float* __restrict__ g1,
      const float* __restrict__ w2, const float* __restrict__ g2, short* __restrict__ wloc){
  int i = blockIdx.x*256 + threadIdx.x;
  int ci = i & 127, row = (i >> 7) % 384, ky = i / 49152;
  int kx = row >> 7, co = row & 127;
  float v = w1[(co*128 + ci)*9 + ky*3 + kx] * g1[co];
  if (ky == 1 && kx == 1) v += w2[co*128 + ci] * g2[co];
  wloc[i] = f2bs(v);
}

// ============ K2: local conv (folded 3x3+1x1), R3 geometry + prefetch ============
__global__ __launch_bounds__(256) void k_localm(const short* __restrict__ hT, const short* __restrict__ wloc,
      const float* __restrict__ b1, const float* __restrict__ b2, float* __restrict__ out){
  int blk = blockIdx.x;
  blk = (blk & 7)*64 + (blk >> 3);          // XCD swizzle (grid 512)
  const int cg = blk & 1, y2 = (blk >> 1) & 63, b = blk >> 7;
  const int t = threadIdx.x, lane = t & 63, wave = t >> 6;
  const int quad = lane >> 4, l15 = lane & 15;
  const int r = wave >> 1, x0w = (wave & 1)*64;
  __shared__ __align__(16) short smem2[22784];
  short* as = smem2;
  short* bs = smem2 + 16640;
  uint4 areg[9], breg[3];
  f32x4 acc[4][4];
  #pragma unroll
  for (int i = 0; i < 4; ++i)
    #pragma unroll
    for (int j = 0; j < 4; ++j) acc[i][j] = (f32x4){0.f,0.f,0.f,0.f};

  auto loadA = [&](int ch){
    const int ci0 = ch*32;
    #pragma unroll
    for (int j = 0; j < 9; ++j){
      int i = t + j*256;
      uint4 val = {0,0,0,0};
      if (i < 2080){
        int sr = i / 520, jj = i - sr*520;
        int col = jj >> 2, cq = jj & 3;
        int g = 2*y2 - 1 + sr;
        if ((unsigned)g < 128u)
          val = *(const uint4*)&hT[((size_t)(b*128+g)*130 + col)*128 + ci0 + cq*8];
      }
      areg[j] = val;
    }
  };
  auto writeA = [&](){
    #pragma unroll
    for (int j = 0; j < 9; ++j){
      int i = t + j*256;
      if (i < 2080){
        int sr = i / 520, jj = i - sr*520;
        int col = jj >> 2, cq = jj & 3;
        *(uint4*)&as[((sr*130 + col)*4 + SLOT(col,cq))*8] = areg[j];
      }
    }
  };
  auto loadB = [&](int ch, int ky){
    const int ci0 = ch*32;
    #pragma unroll
    for (int j = 0; j < 3; ++j){
      int i = t + j*256;
      int rr = i >> 2, cq = i & 3;
      int kk = ky*3 + (rr >> 6), co_l = rr & 63;
      breg[j] = *(const uint4*)&wloc[((size_t)(kk*128 + cg*64 + co_l))*128 + ci0 + cq*8];
    }
  };
  auto writeB = [&](){
    #pragma unroll
    for (int j = 0; j < 3; ++j){
      int i = t + j*256;
      int rr = i >> 2, cq = i & 3;
      *(uint4*)&bs[(rr*4 + SLOT(rr,cq))*8] = breg[j];
    }
  };
  auto compute = [&](int sr){
    #pragma unroll
    for (int kx = 0; kx < 3; ++kx){
      short8 af[4], bf[4];
      #pragma unroll
      for (int mt = 0; mt < 4; ++mt){
        int col = x0w + mt*16 + l15 + kx;
        af[mt] = *(const short8*)&as[((sr*130 + col)*4 + SLOT(col,quad))*8];
      }
      #pragma unroll
      for (int nt = 0; nt < 4; ++nt){
        int rr = kx*64 + nt*16 + l15;
        bf[nt] = *(const short8*)&bs[(rr*4 + SLOT(rr,quad))*8];
      }
      #pragma unroll
      for (int mt = 0; mt < 4; ++mt)
        #pragma unroll
        for (int nt = 0; nt < 4; ++nt)
          acc[mt][nt] = __builtin_amdgcn_mfma_f32_16x16x32_bf16(af[mt], bf[nt], acc[mt][nt], 0, 0, 0);
    }
  };

  loadA(0); loadB(0, 0);
  #pragma unroll 1
  for (int ch = 0; ch < 4; ++ch){
    #pragma unroll 1
    for (int ky = 0; ky < 3; ++ky){
      __syncthreads();
      if (ky == 0) writeA();
      writeB();
      if (ky < 2) loadB(ch, ky+1);
      else if (ch < 3){ loadA(ch+1); loadB(ch+1, 0); }
      __syncthreads();
      compute(r + ky);
    }
  }
  const int Y = 2*y2 + r;
  #pragma unroll
  for (int nt = 0; nt < 4; ++nt){
    int co = cg*64 + nt*16 + l15;
    float bia = b1[co] + b2[co];
    #pragma unroll
    for (int mt = 0; mt < 4; ++mt){
      int xb = x0w + mt*16 + quad*4;
      float4 o4;
      o4.x = acc[mt][nt][0] + bia;
      o4.y = acc[mt][nt][1] + bia;
      o4.z = acc[mt][nt][2] + bia;
      o4.w = acc[mt][nt][3] + bia;
      *(float4*)&out[((size_t)(b*128 + co)*128 + Y)*128 + xb] = o4;
    }
  }
}

// ============ P9: qkv_w fp32 -> bf16 [oc][ci] ============
__global__ __launch_bounds__(256) void k_wqkvrep(const float* __restrict__ w, short* __restrict__ wqkv){
  int i = blockIdx.x*256 + threadIdx.x;
  wqkv[i] = f2bs(w[i]);
}

// ============ K3: qkv 1x1 conv (MFMA GEMM over hT) -> windowed q,k,v ============
__global__ __launch_bounds__(256) void k_qkvm(const short* __restrict__ hT, const short* __restrict__ wqkv,
      bf16* __restrict__ q, bf16* __restrict__ k, bf16* __restrict__ v){
  const int blk = blockIdx.x, ocg = blockIdx.y;
  const int b = blk >> 7, y = blk & 127;
  const int t = threadIdx.x, lane = t & 63, wave = t >> 6;
  const int quad = lane >> 4, l15 = lane & 15;
  const int m0 = (wave >> 1)*64, n0 = (wave & 1)*64;
  __shared__ __align__(16) short asq[4096];   // (col*4 + SLOT(col,cq))*8
  __shared__ __align__(16) short bsq[4096];
  const short* xrow = hT + ((size_t)(b*128 + y)*130 + 1)*128;
  const short* wk   = wqkv + (size_t)ocg*128*128;
  f32x4 acc[4][4];
  #pragma unroll
  for (int i = 0; i < 4; ++i)
    #pragma unroll
    for (int j = 0; j < 4; ++j) acc[i][j] = (f32x4){0.f,0.f,0.f,0.f};
  for (int ch = 0; ch < 4; ++ch){
    const int ci0 = ch*32;
    __syncthreads();
    for (int i = t; i < 512; i += 256){
      int col = i >> 2, cq = i & 3;
      *(uint4*)&asq[(col*4 + SLOT(col,cq))*8] = *(const uint4*)&xrow[col*128 + ci0 + cq*8];
    }
    for (int i = t; i < 512; i += 256){
      int rr = i >> 2, cq = i & 3;
      *(uint4*)&bsq[(rr*4 + SLOT(rr,cq))*8] = *(const uint4*)&wk[rr*128 + ci0 + cq*8];
    }
    __syncthreads();
    short8 af[4], bf[4];
    #pragma unroll
    for (int mt = 0; mt < 4; ++mt){
      int row = m0 + mt*16 + l15;
      af[mt] = *(const short8*)&asq[(row*4 + SLOT(row,quad))*8];
    }
    #pragma unroll
    for (int nt = 0; nt < 4; ++nt){
      int row = n0 + nt*16 + l15;
      bf[nt] = *(const short8*)&bsq[(row*4 + SLOT(row,quad))*8];
    }
    #pragma unroll
    for (int mt = 0; mt < 4; ++mt)
      #pragma unroll
      for (int nt = 0; nt < 4; ++nt)
        acc[mt][nt] = __builtin_amdgcn_mfma_f32_16x16x32_bf16(af[mt], bf[nt], acc[mt][nt], 0, 0, 0);
  }
  bf16* dst = (ocg == 0) ? q : (ocg == 1) ? k : v;
  const int iy = y & 7, hy = y >> 3;
  #pragma unroll
  for (int nt = 0; nt < 4; ++nt){
    int co = n0 + nt*16 + l15;
    int head = co >> 4, d = co & 15;
    #pragma unroll
    for (int mt = 0; mt < 4; ++mt){
      int xb = m0 + mt*16 + quad*4;
      #pragma unroll
      for (int rr = 0; rr < 4; ++rr){
        int x = xb + rr;
        int bw = b*256 + hy*16 + (x >> 3);
        int n = iy*8 + (x & 7);
        dst[((size_t)(bw*8+head)*64 + n)*16 + d] = f2b(acc[mt][nt][rr]);
      }
    }
  }
}

// ============ K4: dots = q.k^T * 0.25 + relpos bias (vectorized) ============
__global__ __launch_bounds__(256) void k_dots(const bf16* __restrict__ q, const bf16* __restrict__ kk,
      const float* __restrict__ rel, bf16* __restrict__ dots){
  const int bw = blockIdx.x, hd = blockIdx.y;
  __shared__ __align__(16) short qs[64][16];
  __shared__ __align__(16) short ks2[64][16];   // octet s of row m at [(s^((m>>4)&1))*8]
  const int t = threadIdx.x;
  const size_t base = (size_t)(bw*8+hd)*1024;
  const short* qp = (const short*)q;
  const short* kp = (const short*)kk;
  if (t < 64){
    *(uint4*)&qs[t][0] = *(const uint4*)&qp[base + t*16];
    *(uint4*)&qs[t][8] = *(const uint4*)&qp[base + t*16 + 8];
  } else if (t < 128){
    int r = t - 64;
    uint4 a0 = *(const uint4*)&kp[base + r*16];
    uint4 a1 = *(const uint4*)&kp[base + r*16 + 8];
    int p = (r >> 4) & 1;
    *(uint4*)&ks2[r][p*8]     = a0;
    *(uint4*)&ks2[r][8 - p*8] = a1;
  }
  __syncthreads();
  const int n = t >> 2, jm = t & 3;
  float qr[16];
  short8 q0 = *(const short8*)&qs[n][0];
  short8 q1 = *(const short8*)&qs[n][8];
  #pragma unroll
  for (int d = 0; d < 8; ++d){ qr[d] = s2f(q0[d]); qr[8+d] = s2f(q1[d]); }
  const int ny = n >> 3, nx = n & 7;
  float a[16];
  #pragma unroll
  for (int mm = 0; mm < 16; ++mm){
    int m = jm*16 + mm;
    int p = (m >> 4) & 1;
    short8 k0 = *(const short8*)&ks2[m][p*8];
    short8 k1 = *(const short8*)&ks2[m][8 - p*8];
    float acc = 0.f;
    #pragma unroll
    for (int d = 0; d < 8; ++d) acc += qr[d]*s2f(k0[d]);
    #pragma unroll
    for (int d = 0; d < 8; ++d) acc += qr[8+d]*s2f(k1[d]);
    int my = m >> 3, mx = m & 7;
    int ridx = (ny - my + 7)*15 + (nx - mx + 7);
    a[mm] = acc*0.25f + rel[ridx*8 + hd];
  }
  short8 s0, s1;
  #pragma unroll
  for (int j = 0; j < 8; ++j){ s0[j] = f2bs(a[j]); s1[j] = f2bs(a[8+j]); }
  short* dp = (short*)dots + base*4 + (size_t)n*64 + jm*16;
  *(short8*)&dp[0] = s0;
  *(short8*)&dp[8] = s1;
}

// ============ K5: fused axis reductions (z1 + z2 + z3 in one pass) ============
__global__ __launch_bounds__(256) void k_zall(const bf16* __restrict__ dots,
      bf16* __restrict__ z1, bf16* __restrict__ z2, bf16* __restrict__ z3){
  const int bw = blockIdx.x;
  const int t = threadIdx.x;
  const int q4 = t >> 2, j4 = t & 3;
  __shared__ float sd[64][65];
  float mx3[16], sm3[16];
  #pragma unroll
  for (int i = 0; i < 16; ++i){ mx3[i] = -1e30f; sm3[i] = 0.f; }
  const short* dp = (const short*)dots + (size_t)bw*32768;
  for (int hd = 0; hd < 8; ++hd){
    __syncthreads();
    const short* p = dp + (size_t)hd*4096;
    #pragma unroll
    for (int g = 0; g < 2; ++g){
      short8 s8 = *(const short8*)&p[t*16 + g*8];
      #pragma unroll
      for (int j = 0; j < 8; ++j){
        float vv = s2f(s8[j]);
        sd[q4][j4*16 + g*8 + j] = vv;
        mx3[g*8+j] = fmaxf(mx3[g*8+j], vv);
        sm3[g*8+j] += vv;
      }
    }
    __syncthreads();
    float mx = -1e30f, sm = 0.f;
    #pragma unroll
    for (int m = 0; m < 16; ++m){
      float vv = sd[q4][j4*16 + m];
      mx = fmaxf(mx, vv); sm += vv;
    }
    mx = fmaxf(mx, __shfl_xor(mx, 1, 4));
    mx = fmaxf(mx, __shfl_xor(mx, 2, 4));
    sm += __shfl_xor(sm, 1, 4);
    sm += __shfl_xor(sm, 2, 4);
    if (j4 == 0){
      z2[(size_t)bw*1024 + q4*8 + hd]       = f2b(mx);
      z2[(size_t)bw*1024 + 512 + q4*8 + hd] = f2b(sm*(1.f/64.f));
    }
    float mxc = -1e30f, smc = 0.f;
    #pragma unroll
    for (int nn = 0; nn < 16; ++nn){
      float vv = sd[j4*16 + nn][q4];
      mxc = fmaxf(mxc, vv); smc += vv;
    }
    mxc = fmaxf(mxc, __shfl_xor(mxc, 1, 4));
    mxc = fmaxf(mxc, __shfl_xor(mxc, 2, 4));
    smc += __shfl_xor(smc, 1, 4);
    smc += __shfl_xor(smc, 2, 4);
    if (j4 == 0){
      z1[(size_t)bw*1024 + hd*64 + q4]       = f2b(mxc);
      z1[(size_t)bw*1024 + 512 + hd*64 + q4] = f2b(smc*(1.f/64.f));
    }
  }
  short* zp = (short*)z3 + (size_t)bw*8192;
  short8 o0, o1, p0, p1;
  #pragma unroll
  for (int j = 0; j < 8; ++j){
    o0[j] = f2bs(mx3[j]);        o1[j] = f2bs(mx3[8+j]);
    p0[j] = f2bs(sm3[j]*0.125f); p1[j] = f2bs(sm3[8+j]*0.125f);
  }
  *(short8*)&zp[t*16]          = o0;
  *(short8*)&zp[t*16 + 8]      = o1;
  *(short8*)&zp[4096 + t*16]   = p0;
  *(short8*)&zp[4096 + t*16+8] = p1;
}

// ============ K6: generic 7x7 2->1 conv + bn + sigmoid (small gates) ============
__global__ __launch_bounds__(256) void k_gate(const bf16* __restrict__ z, const float* __restrict__ w,
      const float* __restrict__ gg, const float* __restrict__ bb, float* __restrict__ G, int R, int C){
  __shared__ float wsm[98];
  const int t = threadIdx.x;
  if (t < 98) wsm[t] = w[t];
  __syncthreads();
  const int bw = blockIdx.x;
  int p = blockIdx.y*256 + t; if (p >= R*C) return;
  int y = p / C, x = p - y*C;
  float acc = 0.f;
  for (int c = 0; c < 2; ++c)
    for (int ky = 0; ky < 7; ++ky){
      int iy = y + ky - 3; if ((unsigned)iy >= (unsigned)R) continue;
      for (int kx = 0; kx < 7; ++kx){
        int ix = x + kx - 3; if ((unsigned)ix >= (unsigned)C) continue;
        acc += b2f(z[((size_t)(bw*2+c)*R + iy)*C + ix]) * wsm[c*49 + ky*7 + kx];
      }
    }
  G[(size_t)bw*R*C + p] = sigm(acc*gg[0] + bb[0]);
}

// ============ K6b: specialized 64x64 gate (G3) ============
__global__ __launch_bounds__(256) void k_gate3(const bf16* __restrict__ z, const float* __restrict__ w,
      const float* __restrict__ gg, const float* __restrict__ bb, float* __restrict__ G){
  const int bw = blockIdx.x;
  __shared__ float pad[2][70][72];
  __shared__ float wsm[98];
  const int t = threadIdx.x;
  if (t < 98) wsm[t] = w[t];
  for (int i = t; i < 2*70*70; i += 256){
    int c = i / 4900, r = i % 4900;
    int py = r / 70, px = r % 70;
    int y = py - 3, x = px - 3;
    float v = 0.f;
    if ((unsigned)y < 64u && (unsigned)x < 64u)
      v = b2f(z[(size_t)bw*8192 + c*4096 + y*64 + x]);
    pad[c][py][px] = v;
  }
  __syncthreads();
  const int tx = t & 15, ty = t >> 4;
  const int x0 = tx*4, y0 = ty*4;
  float acc[4][4] = {};
  #pragma unroll
  for (int c = 0; c < 2; ++c){
    float wr[49];
    #pragma unroll
    for (int kk = 0; kk < 49; ++kk) wr[kk] = wsm[c*49 + kk];
    #pragma unroll
    for (int iy = 0; iy < 10; ++iy){
      float row[10];
      #pragma unroll
      for (int j = 0; j < 10; ++j) row[j] = pad[c][y0+iy][x0+j];
      #pragma unroll
      for (int dy = 0; dy < 4; ++dy){
        const int ky = iy - dy;
        if (ky < 0 || ky > 6) continue;
        #pragma unroll
        for (int kx = 0; kx < 7; ++kx){
          float wv = wr[ky*7 + kx];
          #pragma unroll
          for (int dx = 0; dx < 4; ++dx)
            acc[dy][dx] += wv * row[dx + kx];
        }
      }
    }
  }
  float g0 = gg[0], b0 = bb[0];
  #pragma unroll
  for (int dy = 0; dy < 4; ++dy){
    float4 o4;
    o4.x = sigm(acc[dy][0]*g0 + b0);
    o4.y = sigm(acc[dy][1]*g0 + b0);
    o4.z = sigm(acc[dy][2]*g0 + b0);
    o4.w = sigm(acc[dy][3]*g0 + b0);
    *(float4*)&G[(size_t)bw*4096 + (y0+dy)*64 + x0] = o4;
  }
}

// ============ K7: gated softmax + attn@v -> o (vectorized PV) ============
__global__ __launch_bounds__(256) void k_attn(const bf16* __restrict__ dots, const float* __restrict__ G1,
      const float* __restrict__ G2, const float* __restrict__ G3, const bf16* __restrict__ v,
      float* __restrict__ o){
  const int bw = blockIdx.x, hd = blockIdx.y;
  const int b = bw >> 8, wy = (bw >> 4) & 15, wx = bw & 15;
  __shared__ __align__(16) float attn[64][68];
  __shared__ __align__(16) short vst2[16][64];   // octet o of row d at [(o^(d>>2))*8]
  __shared__ float invTot[64];
  const int t = threadIdx.x;
  const short* vp = (const short*)v;
  for (int i = t; i < 1024; i += 256){
    int m = i >> 4, d = i & 15;
    int oo = m >> 3, rr = m & 7;
    vst2[d][((oo ^ (d >> 2)) << 3) + rr] = vp[(size_t)(bw*8+hd)*1024 + i];
  }
  const int n = t >> 2, j = t & 3;
  float g2v = G2[(size_t)bw*512 + n*8 + hd];
  const short* dp = (const short*)dots + ((size_t)(bw*8+hd)*64 + n)*64 + j*16;
  const float* g1p = G1 + (size_t)bw*512 + hd*64 + j*16;
  const float* g3p = G3 + (size_t)bw*4096 + n*64 + j*16;
  short8 d0 = *(const short8*)&dp[0];
  short8 d1 = *(const short8*)&dp[8];
  float e[16]; float mx = -1e30f;
  #pragma unroll
  for (int m = 0; m < 16; ++m){
    float dv = s2f(m < 8 ? d0[m] : d1[m-8]) * ((g1p[m] + g2v + g3p[m]) * (1.f/3.f));
    e[m] = dv; mx = fmaxf(mx, dv);
  }
  mx = fmaxf(mx, __shfl_xor(mx, 1, 4));
  mx = fmaxf(mx, __shfl_xor(mx, 2, 4));
  float s = 0.f;
  #pragma unroll
  for (int m = 0; m < 16; ++m){ float ev = expf(e[m]-mx); e[m] = ev; s += ev; }
  s += __shfl_xor(s, 1, 4);
  s += __shfl_xor(s, 2, 4);
  #pragma unroll
  for (int m = 0; m < 16; ++m) attn[n][j*16+m] = e[m];
  if (j == 0) invTot[n] = 1.f/s;
  __syncthreads();
  float acc4[4] = {0.f,0.f,0.f,0.f};
  #pragma unroll
  for (int oo = 0; oo < 8; ++oo){
    float4 a0 = *(const float4*)&attn[n][oo*8];
    float4 a1 = *(const float4*)&attn[n][oo*8+4];
    #pragma unroll
    for (int dd = 0; dd < 4; ++dd){
      short8 v8 = *(const short8*)&vst2[j*4+dd][((oo ^ j) << 3)];
      acc4[dd] += a0.x*s2f(v8[0]) + a0.y*s2f(v8[1]) + a0.z*s2f(v8[2]) + a0.w*s2f(v8[3])
                + a1.x*s2f(v8[4]) + a1.y*s2f(v8[5]) + a1.z*s2f(v8[6]) + a1.w*s2f(v8[7]);
    }
  }
  float it = invTot[n];
  int y = wy*8 + (n>>3), x = wx*8 + (n&7);
  #pragma unroll
  for (int dd = 0; dd < 4; ++dd){
    int c = hd*16 + j*4 + dd;
    o[((size_t)(b*128+c)*128 + y)*128 + x] = acc4[dd]*it;
  }
}

// ============ K8: Fh / Fw axial gates ============
__global__ void k_fw(const float* __restrict__ o, float* __restrict__ Fw){
  int t = blockIdx.x*256 + threadIdx.x; if (t >= 4*128*32*128) return;
  int x = t & 127, kk = (t>>7) & 31, bc = t >> 12;
  const float* p = o + ((size_t)bc*128 + kk*4)*128 + x;
  float mx = -1e30f, sm = 0.f;
  #pragma unroll
  for (int r = 0; r < 4; ++r){ float v = p[r*128]; mx = fmaxf(mx,v); sm += v; }
  Fw[t] = sigm(sm*0.25f + mx);
}
__global__ void k_fh(const float* __restrict__ o, float* __restrict__ Fh){
  int t = blockIdx.x*256 + threadIdx.x; if (t >= 4*128*128*32) return;
  int kk = t & 31, y = (t>>5) & 127, bc = t >> 12;
  const float* p = o + ((size_t)bc*128 + y)*128 + kk*4;
  float mx = -1e30f, sm = 0.f;
  #pragma unroll
  for (int r = 0; r < 4; ++r){ float v = p[r]; mx = fmaxf(mx,v); sm += v; }
  Fh[t] = sigm(sm*0.25f + mx);
}

// ============ K9: comb = o * (Fh@Fw) + local ============
__global__ __launch_bounds__(256) void k_comb(const float* __restrict__ o, const float* __restrict__ Fh,
      const float* __restrict__ Fw, const float* __restrict__ local, float* __restrict__ comb){
  const int bc = blockIdx.x;
  __shared__ float fh[128][33];
  __shared__ float fw[32][129];
  const int t = threadIdx.x;
  for (int i = t; i < 4096; i += 256) fh[i>>5][i&31]  = Fh[(size_t)bc*4096 + i];
  for (int i = t; i < 4096; i += 256) fw[i>>7][i&127] = Fw[(size_t)bc*4096 + i];
  __syncthreads();
  for (int i = t; i < 16384; i += 256){
    int y = i >> 7, x = i & 127;
    float g = 0.f;
    #pragma unroll
    for (int kk = 0; kk < 32; ++kk) g += fh[y][kk]*fw[kk][x];
    size_t idx = (size_t)bc*16384 + i;
    comb[idx] = o[idx]*g + local[idx];
  }
}

// ============ K10: reflect-pad + depthwise 8x8 + bn (register-tiled) ============
__global__ __launch_bounds__(256) void k_dw(const float* __restrict__ comb, const float* __restrict__ dw,
      const float* __restrict__ gg, const float* __restrict__ bb, float* __restrict__ out){
  const int bz = blockIdx.y;
  const int oy0 = blockIdx.x*16;
  const int c = bz & 127;
  __shared__ float xs[23][136];
  __shared__ float wsm[64];
  const int t = threadIdx.x;
  if (t < 64) wsm[t] = dw[c*64 + t];
  for (int i = t; i < 23*135; i += 256){
    int py = i / 135, px = i - py*135;
    int gy = oy0 + py - 3, gx = px - 3;
    float v = 0.f;
    if (gy >= 0 && gy <= 128 && gx >= 0 && gx <= 128){
      int yy = (gy==128)?126:gy, xx = (gx==128)?126:gx;
      v = comb[((size_t)bz*128 + yy)*128 + xx];
    }
    xs[py][px] = v;
  }
  __syncthreads();
  const int tx = t & 31, ty = t >> 5;
  const int x0 = tx*4, y0 = ty*2;
  float acc[2][4] = {};
  #pragma unroll
  for (int iy = 0; iy < 9; ++iy){
    float row[12];
    *(float4*)&row[0] = *(const float4*)&xs[y0+iy][x0];
    *(float4*)&row[4] = *(const float4*)&xs[y0+iy][x0+4];
    *(float4*)&row[8] = *(const float4*)&xs[y0+iy][x0+8];
    #pragma unroll
    for (int dy = 0; dy < 2; ++dy){
      const int ky = iy - dy;
      if (ky < 0 || ky > 7) continue;
      #pragma unroll
      for (int kx = 0; kx < 8; ++kx){
        float wv = wsm[ky*8 + kx];
        #pragma unroll
        for (int dx = 0; dx < 4; ++dx)
          acc[dy][dx] += wv * row[dx + kx];
      }
    }
  }
  float g = gg[c], bi = bb[c];
  #pragma unroll
  for (int dy = 0; dy < 2; ++dy){
    float4 o4;
    o4.x = acc[dy][0]*g + bi;
    o4.y = acc[dy][1]*g + bi;
    o4.z = acc[dy][2]*g + bi;
    o4.w = acc[dy][3]*g + bi;
    *(float4*)&out[((size_t)bz*128 + oy0 + y0 + dy)*128 + x0] = o4;
  }
}

// ============ P7: zero omT halo cols ============
__global__ void k_omzero(short* __restrict__ omT){
  int t = blockIdx.x*256 + threadIdx.x;
  int ci = t & 127, side = (t >> 7) & 1, row = t >> 8;
  int cpad = side ? 129 : 0;
  omT[((size_t)row*130 + cpad)*128 + ci] = 0;
}

// ============ P8: repack up_w -> wup[tap][co][ci] bf16 ============
__global__ __launch_bounds__(256) void k_uwrep(const float* __restrict__ w, short* __restrict__ wup){
  int i = blockIdx.x*256 + threadIdx.x;
  int ci = i & 127, co = (i >> 7) & 63, tap = i >> 13;
  wup[i] = f2bs(w[(co*128 + ci)*9 + tap]);
}

// ============ K11: 1x1 proj conv 128->128 -> omT bf16 NHWC+halo ============
__global__ __launch_bounds__(256) void k_pw(const float* __restrict__ p1, const float* __restrict__ w,
      short* __restrict__ omT){
  const int pt = blockIdx.x, cb = blockIdx.y;
  const int P0 = pt*64; const int b = P0 >> 14; const int rem0 = P0 & 16383;
  const int y = rem0 >> 7, x0 = rem0 & 127;
  __shared__ float xsm[128][65];
  __shared__ float wsm[64][129];
  const int tx = threadIdx.x, ty = threadIdx.y, t = ty*16+tx;
  for (int i = t; i < 128*64; i += 256){
    int ci = i >> 6, p = i & 63;
    xsm[ci][p] = p1[(size_t)(b*128+ci)*16384 + rem0 + p];
  }
  for (int i = t; i < 64*128; i += 256){
    int co = i >> 7, ci = i & 127;
    wsm[co][ci] = w[(cb*64+co)*128 + ci];
  }
  __syncthreads();
  float acc[4][4] = {};
  for (int ci = 0; ci < 128; ++ci){
    float hv[4], wv[4];
    #pragma unroll
    for (int jj = 0; jj < 4; ++jj) hv[jj] = xsm[ci][jj*16+tx];
    #pragma unroll
    for (int ii = 0; ii < 4; ++ii) wv[ii] = wsm[ii*16+ty][ci];
    #pragma unroll
    for (int ii = 0; ii < 4; ++ii)
      #pragma unroll
      for (int jj = 0; jj < 4; ++jj) acc[ii][jj] += wv[ii]*hv[jj];
  }
  __syncthreads();
  float* pt_t = &xsm[0][0];
  #pragma unroll
  for (int ii = 0; ii < 4; ++ii)
    #pragma unroll
    for (int jj = 0; jj < 4; ++jj)
      pt_t[(jj*16+tx)*65 + ii*16+ty] = acc[ii][jj];
  __syncthreads();
  for (int i = t; i < 4096; i += 256){
    int px = i >> 6, co_l = i & 63;
    omT[((size_t)(b*128 + y)*130 + x0 + px + 1)*128 + cb*64 + co_l] = f2bs(pt_t[px*65 + co_l]);
  }
}

// ============ K12: transposed 3x3 stride-2 conv 128->64 (MFMA, parity decomp) ============
__global__ __launch_bounds__(256) void k_upm(const short* __restrict__ omT, const short* __restrict__ wup,
      float* __restrict__ out){
  int blk = blockIdx.x;
  blk = (blk & 7)*64 + (blk >> 3);           // XCD swizzle (grid 512)
  const int b = blk >> 7, y = blk & 127;
  const int t = threadIdx.x, lane = t & 63, wave = t >> 6;
  const int quad = lane >> 4, l15 = lane & 15;
  const int m0w = wave*32;
  __shared__ __align__(16) char smem[53504];
  short* asp = (short*)smem;
  short* bsp = (short*)(smem + 16640);
  float* ptile = (float*)smem;
  const int PAR[9] = {3,2,3, 1,0,1, 3,2,3};
  const int ROW[9] = {0,0,0, 0,0,0, 1,1,1};
  const int SHF[9] = {0,0,1, 0,0,1, 0,0,1};
  f32x4 acc[4][2][4];
  #pragma unroll
  for (int p = 0; p < 4; ++p)
    #pragma unroll
    for (int mt = 0; mt < 2; ++mt)
      #pragma unroll
      for (int nt = 0; nt < 4; ++nt) acc[p][mt][nt] = (f32x4){0.f,0.f,0.f,0.f};
  for (int ch = 0; ch < 4; ++ch){
    const int ci0 = ch*32;
    __syncthreads();
    for (int i = t; i < 1040; i += 256){
      int rw = (i >= 520), j = i - rw*520;
      int col = j >> 2, cq = j & 3;
      int row = rw*130 + col;
      uint4 val = {0,0,0,0};
      if (y + rw < 128)
        val = *(const uint4*)&omT[((size_t)(b*128 + y + rw)*130 + col)*128 + ci0 + cq*8];
      *(uint4*)&asp[(row*4 + SLOT(row,cq))*8] = val;
    }
    for (int i = t; i < 2304; i += 256){
      int rr = i >> 2, cq = i & 3;
      *(uint4*)&bsp[(rr*4 + SLOT(rr,cq))*8] = *(const uint4*)&wup[rr*128 + ci0 + cq*8];
    }
    __syncthreads();
    #pragma unroll
    for (int k = 0; k < 9; ++k){
      const int pr = PAR[k], rw = ROW[k], sh = SHF[k];
      if (rw && y == 127) continue;
      short8 af[2], bf[4];
      #pragma unroll
      for (int mt = 0; mt < 2; ++mt){
        int row = rw*130 + m0w + mt*16 + l15 + 1 + sh;
        af[mt] = *(const short8*)&asp[(row*4 + SLOT(row,quad))*8];
      }
      #pragma unroll
      for (int nt = 0; nt < 4; ++nt){
        int row = k*64 + nt*16 + l15;
        bf[nt] = *(const short8*)&bsp[(row*4 + SLOT(row,quad))*8];
      }
      #pragma unroll
      for (int mt = 0; mt < 2; ++mt)
        #pragma unroll
        for (int nt = 0; nt < 4; ++nt)
          acc[pr][mt][nt] = __builtin_amdgcn_mfma_f32_16x16x32_bf16(af[mt], bf[nt], acc[pr][mt][nt], 0, 0, 0);
    }
  }
  #pragma unroll
  for (int p = 0; p < 4; ++p){
    __syncthreads();
    #pragma unroll
    for (int mt = 0; mt < 2; ++mt)
      #pragma unroll
      for (int nt = 0; nt < 4; ++nt){
        int co = nt*16 + l15;
        int xb = m0w + mt*16 + quad*4;
        #pragma unroll
        for (int r = 0; r < 4; ++r)
          ptile[co*132 + xb + r] = acc[p][mt][nt][r];
      }
    __syncthreads();
    int py = p >> 1, px = p & 1;
    int Y = 2*y + py;
    for (int i = t; i < 8192; i += 256){
      int co = i >> 7, xx = i & 127;
      out[((size_t)(b*64 + co)*256 + Y)*256 + 2*xx + px] = ptile[co*132 + xx];
    }
  }
}

extern "C" void kernel_launch(void* const* d_in, const int* in_sizes, int n_in,
                              void* d_out, int out_size, void* d_ws, size_t ws_size,
                              hipStream_t stream) {
  const float* x       = (const float*)d_in[0];
  const float* conv_w  = (const float*)d_in[1];
  const float* bn1_g   = (const float*)d_in[2];
  const float* bn1_b   = (const float*)d_in[3];
  const float* qkv_w   = (const float*)d_in[4];
  const float* loc1_w  = (const float*)d_in[5];
  const float* loc1_g  = (const float*)d_in[6];
  const float* loc1_b  = (const float*)d_in[7];
  const float* loc2_w  = (const float*)d_in[8];
  const float* loc2_g  = (const float*)d_in[9];
  const float* loc2_b  = (const float*)d_in[10];
  const float* rel_t   = (const float*)d_in[11];
  const float* cw_w    = (const float*)d_in[12];
  const float* cw_g    = (const float*)d_in[13];
  const float* cw_b    = (const float*)d_in[14];
  const float* hc_w    = (const float*)d_in[15];
  const float* hc_g    = (const float*)d_in[16];
  const float* hc_b    = (const float*)d_in[17];
  const float* hw_w    = (const float*)d_in[18];
  const float* hw_g    = (const float*)d_in[19];
  const float* hw_b    = (const float*)d_in[20];
  const float* proj_dw = (const float*)d_in[21];
  const float* proj_g  = (const float*)d_in[22];
  const float* proj_b  = (const float*)d_in[23];
  const float* proj_pw = (const float*)d_in[24];
  const float* up_w    = (const float*)d_in[25];

  char* ws = (char*)d_ws;
  float* local  = (float*)(ws + OFF_LOCAL);
  bf16*  q      = (bf16*)(ws + OFF_Q);
  bf16*  k      = (bf16*)(ws + OFF_K);
  bf16*  v      = (bf16*)(ws + OFF_V);
  bf16*  dots   = (bf16*)(ws + OFF_DOTS);
  bf16*  z1     = (bf16*)(ws + OFF_Z1);
  bf16*  z2     = (bf16*)(ws + OFF_Z2);
  bf16*  z3     = (bf16*)(ws + OFF_Z3);
  float* G1     = (float*)(ws + OFF_G1);
  float* G2     = (float*)(ws + OFF_G2);
  float* G3     = (float*)(ws + OFF_G3);
  short* xT     = (short*)(ws + OFF_DOTS);
  short* hT     = (short*)(ws + OFF_HT);
  short* w2bf   = (short*)(ws + OFF_Z1);
  short* wloc   = (short*)(ws + OFF_Z2);
  short* wqkv   = (short*)(ws + OFF_Z3);
  short* omT    = (short*)(ws + OFF_DOTS);
  short* wup    = (short*)(ws + OFF_Z1);
  float* o_img  = (float*)(ws + OFF_Q);
  float* Fh     = (float*)(ws + OFF_DOTS);
  float* Fw     = (float*)(ws + OFF_DOTS + 8388608);
  float* comb   = (float*)(ws + OFF_H);
  float* proj1  = (float*)(ws + OFF_LOCAL);
  float* outp   = (float*)d_out;

  dim3 blk2(16,16);
  k_wrep <<<1152, 256, 0, stream>>>(conv_w, w2bf);
  k_xzero<<<1024, 256, 0, stream>>>(xT);
  k_xrep <<<8192, 256, 0, stream>>>(x, xT);
  k_hzero<<<512, 256, 0, stream>>>(hT);
  k_conv1m<<<512, 256, 0, stream>>>(xT, w2bf, bn1_g, bn1_b, hT);
  k_lwrep<<<576, 256, 0, stream>>>(loc1_w, loc1_g, loc2_w, loc2_g, wloc);
  k_localm<<<512, 256, 0, stream>>>(hT, wloc, loc1_b, loc2_b, local);
  k_wqkvrep<<<192, 256, 0, stream>>>(qkv_w, wqkv);
  k_qkvm <<<dim3(512,3), 256, 0, stream>>>(hT, wqkv, q, k, v);
  k_dots <<<dim3(NWIN,8), 256, 0, stream>>>(q, k, rel_t, dots);
  k_zall <<<NWIN, 256, 0, stream>>>(dots, z1, z2, z3);
  k_gate <<<dim3(NWIN,2),  256, 0, stream>>>(z1, cw_w, cw_g, cw_b, G1, 8, 64);
  k_gate <<<dim3(NWIN,2),  256, 0, stream>>>(z2, hc_w, hc_g, hc_b, G2, 64, 8);
  k_gate3<<<NWIN, 256, 0, stream>>>(z3, hw_w, hw_g, hw_b, G3);
  k_attn <<<dim3(NWIN,8), 256, 0, stream>>>(dots, G1, G2, G3, v, o_img);
  k_fw   <<<8192, 256, 0, stream>>>(o_img, Fw);
  k_fh   <<<8192, 256, 0, stream>>>(o_img, Fh);
  k_comb <<<512, 256, 0, stream>>>(o_img, Fh, Fw, local, comb);
  k_dw   <<<dim3(8, BB*128), 256, 0, stream>>>(comb, proj_dw, proj_g, proj_b, proj1);
  k_omzero<<<512, 256, 0, stream>>>(omT);
  k_uwrep<<<288, 256, 0, stream>>>(up_w, wup);
  k_pw   <<<dim3(1024,2), blk2, 0, stream>>>(proj1, proj_pw, omT);
  k_upm  <<<512, 256, 0, stream>>>(omT, wup, outp);
}

// Round 7
// 633.468 us; speedup vs baseline: 1.0946x; 1.0946x over previous
//
#include <hip/hip_runtime.h>
#include <hip/hip_bf16.h>

typedef __hip_bfloat16 bf16;
typedef __attribute__((ext_vector_type(8))) short short8;
typedef __attribute__((ext_vector_type(4))) float f32x4;

#define DEV __device__ __forceinline__
DEV float b2f(bf16 v){ return __bfloat162float(v); }
DEV bf16 f2b(float v){ return __float2bfloat16(v); }
DEV short f2bs(float v){ union{ bf16 b; short s; } u; u.b = __float2bfloat16(v); return u.s; }
DEV float s2f(short s){ union{ short s; bf16 b; } u; u.s = s; return __bfloat162float(u.b); }
DEV float sigm(float x){ return 1.f/(1.f + expf(-x)); }

// ---- problem constants ----
#define BB 4
#define CIN 256
#define MID 128
#define COUT 64
#define HH 128
#define WW 128
#define WS 8
#define HEADS 8
#define HD 16
#define NTOK 64
#define NWIN 1024

// LDS slot swizzle: row-major 64B rows, slot = cq ^ ((row>>1)&3)
#define SLOT(row,cq) ((cq) ^ (((row)>>1)&3))

// ---- workspace layout (bytes) ----
static const size_t OFF_H     = 0;
static const size_t OFF_LOCAL = 33554432;
static const size_t OFF_Q     = 67108864;
static const size_t OFF_K     = 83886080;
static const size_t OFF_V     = 100663296;
static const size_t OFF_DOTS  = 117440512;
static const size_t OFF_Z1    = 184549376;
static const size_t OFF_Z2    = 186646528;
static const size_t OFF_Z3    = 188743680;
static const size_t OFF_G1    = 205520896;
static const size_t OFF_G2    = 207618048;
static const size_t OFF_G3    = 209715200;
static const size_t OFF_HT    = OFF_DOTS + 34078720;

// ============ P1: repack conv_w -> w2[kk][co][ci] bf16 ============
__global__ __launch_bounds__(256) void k_wrep(const float* __restrict__ w, short* __restrict__ w2){
  int i = blockIdx.x*256 + threadIdx.x;
  int ci = i & 255, co = (i >> 8) & 127, kk = i >> 15;
  w2[i] = f2bs(w[(co*256 + ci)*9 + kk]);
}

// ============ P2: zero pad columns of xT ============
__global__ void k_xzero(short* __restrict__ xT){
  int t = blockIdx.x*256 + threadIdx.x;
  int ci = t & 255, side = (t >> 8) & 1, row = t >> 9;
  int cpad = side ? 129 : 0;
  xT[((size_t)row*130 + cpad)*256 + ci] = 0;
}

// ============ P3: x NCHW fp32 -> xT[b][r][c+1][ci] bf16 ============
__global__ __launch_bounds__(256) void k_xrep(const float* __restrict__ x, short* __restrict__ xT){
  const int blk = blockIdx.x;
  const int cgrp = blk & 1, cig = (blk >> 1) & 7, r = (blk >> 4) & 127, b = blk >> 11;
  const int c0 = cgrp*64, ci0 = cig*32;
  __shared__ float lds[32][65];
  const int t = threadIdx.x;
  for (int i = t; i < 2048; i += 256){
    int lci = i >> 6, c = i & 63;
    lds[lci][c] = x[((size_t)(b*256 + ci0 + lci)*128 + r)*128 + c0 + c];
  }
  __syncthreads();
  for (int i = t; i < 2048; i += 256){
    int lci = i & 31, cc = i >> 5;
    xT[((size_t)(b*128 + r)*130 + c0 + cc + 1)*256 + ci0 + lci] = f2bs(lds[lci][cc]);
  }
}

// ============ K1: conv3x3 256->128 + bn + relu -> hT bf16 ============
// 1-row co-split blocks (grid 1024, high occupancy) + SLOT-swizzled LDS (conflict-free).
__global__ __launch_bounds__(256) void k_conv1m(const short* __restrict__ xT, const short* __restrict__ w2,
      const float* __restrict__ gg, const float* __restrict__ bb, short* __restrict__ hT){
  int blk = blockIdx.x;
  blk = (blk & 7)*128 + (blk >> 3);          // XCD swizzle (grid 1024)
  const int cg = blk & 1, y = (blk >> 1) & 127, b = blk >> 8;
  const int t = threadIdx.x, lane = t & 63, wave = t >> 6;
  const int quad = lane >> 4, l15 = lane & 15;
  const int m0 = wave*32;
  __shared__ __align__(16) short smem[10304];   // as 130*32 + bs 192*32
  short* as = smem;           // (col*4 + SLOT(col,cq))*8
  short* bs = smem + 4160;    // (rr*4 + SLOT(rr,cq))*8, rr = kx*64+co_l
  f32x4 acc[2][4];
  #pragma unroll
  for (int i = 0; i < 2; ++i)
    #pragma unroll
    for (int j = 0; j < 4; ++j) acc[i][j] = (f32x4){0.f,0.f,0.f,0.f};
  for (int ky = 0; ky < 3; ++ky){
    int r = y + ky - 1;
    if ((unsigned)r >= 128u) continue;
    const short* xrow = xT + (size_t)(b*128 + r)*130*256;
    const short* wk   = w2 + (size_t)(ky*384 + cg*64)*256;
    for (int ch = 0; ch < 8; ++ch){
      const int ci0 = ch*32;
      __syncthreads();
      for (int i = t; i < 520; i += 256){
        int col = i >> 2, cq = i & 3;
        *(uint4*)&as[(col*4 + SLOT(col,cq))*8] = *(const uint4*)&xrow[col*256 + ci0 + cq*8];
      }
      for (int i = t; i < 768; i += 256){
        int rr = i >> 2, cq = i & 3;
        *(uint4*)&bs[(rr*4 + SLOT(rr,cq))*8] =
          *(const uint4*)&wk[(((rr >> 6)<<7) + (rr & 63))*256 + ci0 + cq*8];
      }
      __syncthreads();
      #pragma unroll
      for (int kx = 0; kx < 3; ++kx){
        short8 af[2], bf[4];
        #pragma unroll
        for (int mt = 0; mt < 2; ++mt){
          int col = m0 + mt*16 + l15 + kx;
          af[mt] = *(const short8*)&as[(col*4 + SLOT(col,quad))*8];
        }
        #pragma unroll
        for (int nt = 0; nt < 4; ++nt){
          int rr = kx*64 + nt*16 + l15;
          bf[nt] = *(const short8*)&bs[(rr*4 + SLOT(rr,quad))*8];
        }
        #pragma unroll
        for (int mt = 0; mt < 2; ++mt)
          #pragma unroll
          for (int nt = 0; nt < 4; ++nt)
            acc[mt][nt] = __builtin_amdgcn_mfma_f32_16x16x32_bf16(af[mt], bf[nt], acc[mt][nt], 0, 0, 0);
      }
    }
  }
  // epilogue: bn+relu, transpose via LDS, write bf16 NHWC rows of hT
  __syncthreads();
  short* tb = smem;   // [128][72] bf16 (x, co_local)
  #pragma unroll
  for (int nt = 0; nt < 4; ++nt){
    int cl = nt*16 + l15, co = cg*64 + cl;
    float g = gg[co], bia = bb[co];
    #pragma unroll
    for (int mt = 0; mt < 2; ++mt){
      int xb = m0 + mt*16 + quad*4;
      #pragma unroll
      for (int r2 = 0; r2 < 4; ++r2)
        tb[(xb + r2)*72 + cl] = f2bs(fmaxf(acc[mt][nt][r2]*g + bia, 0.f));
    }
  }
  __syncthreads();
  for (int i = t; i < 1024; i += 256){
    int xx = i >> 3, c8 = i & 7;
    *(uint4*)&hT[((size_t)(b*128 + y)*130 + xx + 1)*128 + cg*64 + c8*8] = *(const uint4*)&tb[xx*72 + c8*8];
  }
}

// ============ P4: zero pad columns of hT ============
__global__ void k_hzero(short* __restrict__ hT){
  int t = blockIdx.x*256 + threadIdx.x;
  int ci = t & 127, side = (t >> 7) & 1, row = t >> 8;
  int cpad = side ? 129 : 0;
  hT[((size_t)row*130 + cpad)*128 + ci] = 0;
}

// ============ P6: fold local weights: wloc[kk][co][ci] bf16 ============
__global__ __launch_bounds__(256) void k_lwrep(const float* __restrict__ w1, const float* __restrict__ g1,
      const float* __restrict__ w2, const float* __restrict__ g2, short* __restrict__ wloc){
  int i = blockIdx.x*256 + threadIdx.x;
  int ci = i & 127, row = (i >> 7) % 384, ky = i / 49152;
  int kx = row >> 7, co = row & 127;
  float v = w1[(co*128 + ci)*9 + ky*3 + kx] * g1[co];
  if (ky == 1 && kx == 1) v += w2[co*128 + ci] * g2[co];
  wloc[i] = f2bs(v);
}

// ============ K2: local conv (folded 3x3+1x1), 1-row blocks, SLOT LDS ============
__global__ __launch_bounds__(256) void k_localm(const short* __restrict__ hT, const short* __restrict__ wloc,
      const float* __restrict__ b1, const float* __restrict__ b2, float* __restrict__ out){
  int blk = blockIdx.x;
  blk = (blk & 7)*128 + (blk >> 3);          // XCD swizzle (grid 1024)
  const int cg = blk & 1, y = (blk >> 1) & 127, b = blk >> 8;
  const int t = threadIdx.x, lane = t & 63, wave = t >> 6;
  const int quad = lane >> 4, l15 = lane & 15;
  const int m0 = wave*32;
  __shared__ __align__(16) short smem2[10304];
  short* as = smem2;
  short* bs = smem2 + 4160;
  f32x4 acc[2][4];
  #pragma unroll
  for (int i = 0; i < 2; ++i)
    #pragma unroll
    for (int j = 0; j < 4; ++j) acc[i][j] = (f32x4){0.f,0.f,0.f,0.f};
  for (int ky = 0; ky < 3; ++ky){
    int r = y + ky - 1;
    if ((unsigned)r >= 128u) continue;
    const short* xrow = hT + (size_t)(b*128 + r)*130*128;
    const short* wk   = wloc + (size_t)(ky*384 + cg*64)*128;
    for (int ch = 0; ch < 4; ++ch){
      const int ci0 = ch*32;
      __syncthreads();
      for (int i = t; i < 520; i += 256){
        int col = i >> 2, cq = i & 3;
        *(uint4*)&as[(col*4 + SLOT(col,cq))*8] = *(const uint4*)&xrow[col*128 + ci0 + cq*8];
      }
      for (int i = t; i < 768; i += 256){
        int rr = i >> 2, cq = i & 3;
        *(uint4*)&bs[(rr*4 + SLOT(rr,cq))*8] =
          *(const uint4*)&wk[(((rr >> 6)<<7) + (rr & 63))*128 + ci0 + cq*8];
      }
      __syncthreads();
      #pragma unroll
      for (int kx = 0; kx < 3; ++kx){
        short8 af[2], bf[4];
        #pragma unroll
        for (int mt = 0; mt < 2; ++mt){
          int col = m0 + mt*16 + l15 + kx;
          af[mt] = *(const short8*)&as[(col*4 + SLOT(col,quad))*8];
        }
        #pragma unroll
        for (int nt = 0; nt < 4; ++nt){
          int rr = kx*64 + nt*16 + l15;
          bf[nt] = *(const short8*)&bs[(rr*4 + SLOT(rr,quad))*8];
        }
        #pragma unroll
        for (int mt = 0; mt < 2; ++mt)
          #pragma unroll
          for (int nt = 0; nt < 4; ++nt)
            acc[mt][nt] = __builtin_amdgcn_mfma_f32_16x16x32_bf16(af[mt], bf[nt], acc[mt][nt], 0, 0, 0);
      }
    }
  }
  #pragma unroll
  for (int nt = 0; nt < 4; ++nt){
    int co = cg*64 + nt*16 + l15;
    float bia = b1[co] + b2[co];
    #pragma unroll
    for (int mt = 0; mt < 2; ++mt){
      int xb = m0 + mt*16 + quad*4;
      float4 o4;
      o4.x = acc[mt][nt][0] + bia;
      o4.y = acc[mt][nt][1] + bia;
      o4.z = acc[mt][nt][2] + bia;
      o4.w = acc[mt][nt][3] + bia;
      *(float4*)&out[((size_t)(b*128 + co)*128 + y)*128 + xb] = o4;
    }
  }
}

// ============ P9: qkv_w fp32 -> bf16 [oc][ci] ============
__global__ __launch_bounds__(256) void k_wqkvrep(const float* __restrict__ w, short* __restrict__ wqkv){
  int i = blockIdx.x*256 + threadIdx.x;
  wqkv[i] = f2bs(w[i]);
}

// ============ K3: qkv 1x1 conv (MFMA GEMM over hT) -> windowed q,k,v ============
__global__ __launch_bounds__(256) void k_qkvm(const short* __restrict__ hT, const short* __restrict__ wqkv,
      bf16* __restrict__ q, bf16* __restrict__ k, bf16* __restrict__ v){
  const int blk = blockIdx.x, ocg = blockIdx.y;
  const int b = blk >> 7, y = blk & 127;
  const int t = threadIdx.x, lane = t & 63, wave = t >> 6;
  const int quad = lane >> 4, l15 = lane & 15;
  const int m0 = (wave >> 1)*64, n0 = (wave & 1)*64;
  __shared__ __align__(16) short asq[4096];   // (col*4 + SLOT(col,cq))*8
  __shared__ __align__(16) short bsq[4096];
  const short* xrow = hT + ((size_t)(b*128 + y)*130 + 1)*128;
  const short* wk   = wqkv + (size_t)ocg*128*128;
  f32x4 acc[4][4];
  #pragma unroll
  for (int i = 0; i < 4; ++i)
    #pragma unroll
    for (int j = 0; j < 4; ++j) acc[i][j] = (f32x4){0.f,0.f,0.f,0.f};
  for (int ch = 0; ch < 4; ++ch){
    const int ci0 = ch*32;
    __syncthreads();
    for (int i = t; i < 512; i += 256){
      int col = i >> 2, cq = i & 3;
      *(uint4*)&asq[(col*4 + SLOT(col,cq))*8] = *(const uint4*)&xrow[col*128 + ci0 + cq*8];
    }
    for (int i = t; i < 512; i += 256){
      int rr = i >> 2, cq = i & 3;
      *(uint4*)&bsq[(rr*4 + SLOT(rr,cq))*8] = *(const uint4*)&wk[rr*128 + ci0 + cq*8];
    }
    __syncthreads();
    short8 af[4], bf[4];
    #pragma unroll
    for (int mt = 0; mt < 4; ++mt){
      int row = m0 + mt*16 + l15;
      af[mt] = *(const short8*)&asq[(row*4 + SLOT(row,quad))*8];
    }
    #pragma unroll
    for (int nt = 0; nt < 4; ++nt){
      int row = n0 + nt*16 + l15;
      bf[nt] = *(const short8*)&bsq[(row*4 + SLOT(row,quad))*8];
    }
    #pragma unroll
    for (int mt = 0; mt < 4; ++mt)
      #pragma unroll
      for (int nt = 0; nt < 4; ++nt)
        acc[mt][nt] = __builtin_amdgcn_mfma_f32_16x16x32_bf16(af[mt], bf[nt], acc[mt][nt], 0, 0, 0);
  }
  bf16* dst = (ocg == 0) ? q : (ocg == 1) ? k : v;
  const int iy = y & 7, hy = y >> 3;
  #pragma unroll
  for (int nt = 0; nt < 4; ++nt){
    int co = n0 + nt*16 + l15;
    int head = co >> 4, d = co & 15;
    #pragma unroll
    for (int mt = 0; mt < 4; ++mt){
      int xb = m0 + mt*16 + quad*4;
      #pragma unroll
      for (int rr = 0; rr < 4; ++rr){
        int x = xb + rr;
        int bw = b*256 + hy*16 + (x >> 3);
        int n = iy*8 + (x & 7);
        dst[((size_t)(bw*8+head)*64 + n)*16 + d] = f2b(acc[mt][nt][rr]);
      }
    }
  }
}

// ============ K4: dots = q.k^T * 0.25 + relpos bias (vectorized) ============
__global__ __launch_bounds__(256) void k_dots(const bf16* __restrict__ q, const bf16* __restrict__ kk,
      const float* __restrict__ rel, bf16* __restrict__ dots){
  const int bw = blockIdx.x, hd = blockIdx.y;
  __shared__ __align__(16) short qs[64][16];
  __shared__ __align__(16) short ks2[64][16];   // octet s of row m at [(s^((m>>4)&1))*8]
  const int t = threadIdx.x;
  const size_t base = (size_t)(bw*8+hd)*1024;
  const short* qp = (const short*)q;
  const short* kp = (const short*)kk;
  if (t < 64){
    *(uint4*)&qs[t][0] = *(const uint4*)&qp[base + t*16];
    *(uint4*)&qs[t][8] = *(const uint4*)&qp[base + t*16 + 8];
  } else if (t < 128){
    int r = t - 64;
    uint4 a0 = *(const uint4*)&kp[base + r*16];
    uint4 a1 = *(const uint4*)&kp[base + r*16 + 8];
    int p = (r >> 4) & 1;
    *(uint4*)&ks2[r][p*8]     = a0;
    *(uint4*)&ks2[r][8 - p*8] = a1;
  }
  __syncthreads();
  const int n = t >> 2, jm = t & 3;
  float qr[16];
  short8 q0 = *(const short8*)&qs[n][0];
  short8 q1 = *(const short8*)&qs[n][8];
  #pragma unroll
  for (int d = 0; d < 8; ++d){ qr[d] = s2f(q0[d]); qr[8+d] = s2f(q1[d]); }
  const int ny = n >> 3, nx = n & 7;
  float a[16];
  #pragma unroll
  for (int mm = 0; mm < 16; ++mm){
    int m = jm*16 + mm;
    int p = (m >> 4) & 1;
    short8 k0 = *(const short8*)&ks2[m][p*8];
    short8 k1 = *(const short8*)&ks2[m][8 - p*8];
    float acc = 0.f;
    #pragma unroll
    for (int d = 0; d < 8; ++d) acc += qr[d]*s2f(k0[d]);
    #pragma unroll
    for (int d = 0; d < 8; ++d) acc += qr[8+d]*s2f(k1[d]);
    int my = m >> 3, mx = m & 7;
    int ridx = (ny - my + 7)*15 + (nx - mx + 7);
    a[mm] = acc*0.25f + rel[ridx*8 + hd];
  }
  short8 s0, s1;
  #pragma unroll
  for (int j = 0; j < 8; ++j){ s0[j] = f2bs(a[j]); s1[j] = f2bs(a[8+j]); }
  short* dp = (short*)dots + base*4 + (size_t)n*64 + jm*16;
  *(short8*)&dp[0] = s0;
  *(short8*)&dp[8] = s1;
}

// ============ K5: fused axis reductions (z1 + z2 + z3 in one pass) ============
__global__ __launch_bounds__(256) void k_zall(const bf16* __restrict__ dots,
      bf16* __restrict__ z1, bf16* __restrict__ z2, bf16* __restrict__ z3){
  const int bw = blockIdx.x;
  const int t = threadIdx.x;
  const int q4 = t >> 2, j4 = t & 3;
  __shared__ float sd[64][65];
  float mx3[16], sm3[16];
  #pragma unroll
  for (int i = 0; i < 16; ++i){ mx3[i] = -1e30f; sm3[i] = 0.f; }
  const short* dp = (const short*)dots + (size_t)bw*32768;
  for (int hd = 0; hd < 8; ++hd){
    __syncthreads();
    const short* p = dp + (size_t)hd*4096;
    #pragma unroll
    for (int g = 0; g < 2; ++g){
      short8 s8 = *(const short8*)&p[t*16 + g*8];
      #pragma unroll
      for (int j = 0; j < 8; ++j){
        float vv = s2f(s8[j]);
        sd[q4][j4*16 + g*8 + j] = vv;
        mx3[g*8+j] = fmaxf(mx3[g*8+j], vv);
        sm3[g*8+j] += vv;
      }
    }
    __syncthreads();
    float mx = -1e30f, sm = 0.f;
    #pragma unroll
    for (int m = 0; m < 16; ++m){
      float vv = sd[q4][j4*16 + m];
      mx = fmaxf(mx, vv); sm += vv;
    }
    mx = fmaxf(mx, __shfl_xor(mx, 1, 4));
    mx = fmaxf(mx, __shfl_xor(mx, 2, 4));
    sm += __shfl_xor(sm, 1, 4);
    sm += __shfl_xor(sm, 2, 4);
    if (j4 == 0){
      z2[(size_t)bw*1024 + q4*8 + hd]       = f2b(mx);
      z2[(size_t)bw*1024 + 512 + q4*8 + hd] = f2b(sm*(1.f/64.f));
    }
    float mxc = -1e30f, smc = 0.f;
    #pragma unroll
    for (int nn = 0; nn < 16; ++nn){
      float vv = sd[j4*16 + nn][q4];
      mxc = fmaxf(mxc, vv); smc += vv;
    }
    mxc = fmaxf(mxc, __shfl_xor(mxc, 1, 4));
    mxc = fmaxf(mxc, __shfl_xor(mxc, 2, 4));
    smc += __shfl_xor(smc, 1, 4);
    smc += __shfl_xor(smc, 2, 4);
    if (j4 == 0){
      z1[(size_t)bw*1024 + hd*64 + q4]       = f2b(mxc);
      z1[(size_t)bw*1024 + 512 + hd*64 + q4] = f2b(smc*(1.f/64.f));
    }
  }
  short* zp = (short*)z3 + (size_t)bw*8192;
  short8 o0, o1, p0, p1;
  #pragma unroll
  for (int j = 0; j < 8; ++j){
    o0[j] = f2bs(mx3[j]);        o1[j] = f2bs(mx3[8+j]);
    p0[j] = f2bs(sm3[j]*0.125f); p1[j] = f2bs(sm3[8+j]*0.125f);
  }
  *(short8*)&zp[t*16]          = o0;
  *(short8*)&zp[t*16 + 8]      = o1;
  *(short8*)&zp[4096 + t*16]   = p0;
  *(short8*)&zp[4096 + t*16+8] = p1;
}

// ============ K6: generic 7x7 2->1 conv + bn + sigmoid (small gates) ============
__global__ __launch_bounds__(256) void k_gate(const bf16* __restrict__ z, const float* __restrict__ w,
      const float* __restrict__ gg, const float* __restrict__ bb, float* __restrict__ G, int R, int C){
  __shared__ float wsm[98];
  const int t = threadIdx.x;
  if (t < 98) wsm[t] = w[t];
  __syncthreads();
  const int bw = blockIdx.x;
  int p = blockIdx.y*256 + t; if (p >= R*C) return;
  int y = p / C, x = p - y*C;
  float acc = 0.f;
  for (int c = 0; c < 2; ++c)
    for (int ky = 0; ky < 7; ++ky){
      int iy = y + ky - 3; if ((unsigned)iy >= (unsigned)R) continue;
      for (int kx = 0; kx < 7; ++kx){
        int ix = x + kx - 3; if ((unsigned)ix >= (unsigned)C) continue;
        acc += b2f(z[((size_t)(bw*2+c)*R + iy)*C + ix]) * wsm[c*49 + ky*7 + kx];
      }
    }
  G[(size_t)bw*R*C + p] = sigm(acc*gg[0] + bb[0]);
}

// ============ K6b: specialized 64x64 gate (G3) ============
__global__ __launch_bounds__(256) void k_gate3(const bf16* __restrict__ z, const float* __restrict__ w,
      const float* __restrict__ gg, const float* __restrict__ bb, float* __restrict__ G){
  const int bw = blockIdx.x;
  __shared__ float pad[2][70][72];
  __shared__ float wsm[98];
  const int t = threadIdx.x;
  if (t < 98) wsm[t] = w[t];
  for (int i = t; i < 2*70*70; i += 256){
    int c = i / 4900, r = i % 4900;
    int py = r / 70, px = r % 70;
    int y = py - 3, x = px - 3;
    float v = 0.f;
    if ((unsigned)y < 64u && (unsigned)x < 64u)
      v = b2f(z[(size_t)bw*8192 + c*4096 + y*64 + x]);
    pad[c][py][px] = v;
  }
  __syncthreads();
  const int tx = t & 15, ty = t >> 4;
  const int x0 = tx*4, y0 = ty*4;
  float acc[4][4] = {};
  #pragma unroll
  for (int c = 0; c < 2; ++c){
    float wr[49];
    #pragma unroll
    for (int kk = 0; kk < 49; ++kk) wr[kk] = wsm[c*49 + kk];
    #pragma unroll
    for (int iy = 0; iy < 10; ++iy){
      float row[10];
      #pragma unroll
      for (int j = 0; j < 10; ++j) row[j] = pad[c][y0+iy][x0+j];
      #pragma unroll
      for (int dy = 0; dy < 4; ++dy){
        const int ky = iy - dy;
        if (ky < 0 || ky > 6) continue;
        #pragma unroll
        for (int kx = 0; kx < 7; ++kx){
          float wv = wr[ky*7 + kx];
          #pragma unroll
          for (int dx = 0; dx < 4; ++dx)
            acc[dy][dx] += wv * row[dx + kx];
        }
      }
    }
  }
  float g0 = gg[0], b0 = bb[0];
  #pragma unroll
  for (int dy = 0; dy < 4; ++dy){
    float4 o4;
    o4.x = sigm(acc[dy][0]*g0 + b0);
    o4.y = sigm(acc[dy][1]*g0 + b0);
    o4.z = sigm(acc[dy][2]*g0 + b0);
    o4.w = sigm(acc[dy][3]*g0 + b0);
    *(float4*)&G[(size_t)bw*4096 + (y0+dy)*64 + x0] = o4;
  }
}

// ============ K7: gated softmax + attn@v -> o (vectorized PV) ============
__global__ __launch_bounds__(256) void k_attn(const bf16* __restrict__ dots, const float* __restrict__ G1,
      const float* __restrict__ G2, const float* __restrict__ G3, const bf16* __restrict__ v,
      float* __restrict__ o){
  const int bw = blockIdx.x, hd = blockIdx.y;
  const int b = bw >> 8, wy = (bw >> 4) & 15, wx = bw & 15;
  __shared__ __align__(16) float attn[64][68];
  __shared__ __align__(16) short vst2[16][64];   // octet o of row d at [(o^(d>>2))*8]
  __shared__ float invTot[64];
  const int t = threadIdx.x;
  const short* vp = (const short*)v;
  for (int i = t; i < 1024; i += 256){
    int m = i >> 4, d = i & 15;
    int oo = m >> 3, rr = m & 7;
    vst2[d][((oo ^ (d >> 2)) << 3) + rr] = vp[(size_t)(bw*8+hd)*1024 + i];
  }
  const int n = t >> 2, j = t & 3;
  float g2v = G2[(size_t)bw*512 + n*8 + hd];
  const short* dp = (const short*)dots + ((size_t)(bw*8+hd)*64 + n)*64 + j*16;
  const float* g1p = G1 + (size_t)bw*512 + hd*64 + j*16;
  const float* g3p = G3 + (size_t)bw*4096 + n*64 + j*16;
  short8 d0 = *(const short8*)&dp[0];
  short8 d1 = *(const short8*)&dp[8];
  float e[16]; float mx = -1e30f;
  #pragma unroll
  for (int m = 0; m < 16; ++m){
    float dv = s2f(m < 8 ? d0[m] : d1[m-8]) * ((g1p[m] + g2v + g3p[m]) * (1.f/3.f));
    e[m] = dv; mx = fmaxf(mx, dv);
  }
  mx = fmaxf(mx, __shfl_xor(mx, 1, 4));
  mx = fmaxf(mx, __shfl_xor(mx, 2, 4));
  float s = 0.f;
  #pragma unroll
  for (int m = 0; m < 16; ++m){ float ev = expf(e[m]-mx); e[m] = ev; s += ev; }
  s += __shfl_xor(s, 1, 4);
  s += __shfl_xor(s, 2, 4);
  #pragma unroll
  for (int m = 0; m < 16; ++m) attn[n][j*16+m] = e[m];
  if (j == 0) invTot[n] = 1.f/s;
  __syncthreads();
  float acc4[4] = {0.f,0.f,0.f,0.f};
  #pragma unroll
  for (int oo = 0; oo < 8; ++oo){
    float4 a0 = *(const float4*)&attn[n][oo*8];
    float4 a1 = *(const float4*)&attn[n][oo*8+4];
    #pragma unroll
    for (int dd = 0; dd < 4; ++dd){
      short8 v8 = *(const short8*)&vst2[j*4+dd][((oo ^ j) << 3)];
      acc4[dd] += a0.x*s2f(v8[0]) + a0.y*s2f(v8[1]) + a0.z*s2f(v8[2]) + a0.w*s2f(v8[3])
                + a1.x*s2f(v8[4]) + a1.y*s2f(v8[5]) + a1.z*s2f(v8[6]) + a1.w*s2f(v8[7]);
    }
  }
  float it = invTot[n];
  int y = wy*8 + (n>>3), x = wx*8 + (n&7);
  #pragma unroll
  for (int dd = 0; dd < 4; ++dd){
    int c = hd*16 + j*4 + dd;
    o[((size_t)(b*128+c)*128 + y)*128 + x] = acc4[dd]*it;
  }
}

// ============ K8: Fh / Fw axial gates ============
__global__ void k_fw(const float* __restrict__ o, float* __restrict__ Fw){
  int t = blockIdx.x*256 + threadIdx.x; if (t >= 4*128*32*128) return;
  int x = t & 127, kk = (t>>7) & 31, bc = t >> 12;
  const float* p = o + ((size_t)bc*128 + kk*4)*128 + x;
  float mx = -1e30f, sm = 0.f;
  #pragma unroll
  for (int r = 0; r < 4; ++r){ float v = p[r*128]; mx = fmaxf(mx,v); sm += v; }
  Fw[t] = sigm(sm*0.25f + mx);
}
__global__ void k_fh(const float* __restrict__ o, float* __restrict__ Fh){
  int t = blockIdx.x*256 + threadIdx.x; if (t >= 4*128*128*32) return;
  int kk = t & 31, y = (t>>5) & 127, bc = t >> 12;
  const float* p = o + ((size_t)bc*128 + y)*128 + kk*4;
  float mx = -1e30f, sm = 0.f;
  #pragma unroll
  for (int r = 0; r < 4; ++r){ float v = p[r]; mx = fmaxf(mx,v); sm += v; }
  Fh[t] = sigm(sm*0.25f + mx);
}

// ============ K9: comb = o * (Fh@Fw) + local ============
__global__ __launch_bounds__(256) void k_comb(const float* __restrict__ o, const float* __restrict__ Fh,
      const float* __restrict__ Fw, const float* __restrict__ local, float* __restrict__ comb){
  const int bc = blockIdx.x;
  __shared__ float fh[128][33];
  __shared__ float fw[32][129];
  const int t = threadIdx.x;
  for (int i = t; i < 4096; i += 256) fh[i>>5][i&31]  = Fh[(size_t)bc*4096 + i];
  for (int i = t; i < 4096; i += 256) fw[i>>7][i&127] = Fw[(size_t)bc*4096 + i];
  __syncthreads();
  for (int i = t; i < 16384; i += 256){
    int y = i >> 7, x = i & 127;
    float g = 0.f;
    #pragma unroll
    for (int kk = 0; kk < 32; ++kk) g += fh[y][kk]*fw[kk][x];
    size_t idx = (size_t)bc*16384 + i;
    comb[idx] = o[idx]*g + local[idx];
  }
}

// ============ K10: reflect-pad + depthwise 8x8 + bn (register-tiled) ============
__global__ __launch_bounds__(256) void k_dw(const float* __restrict__ comb, const float* __restrict__ dw,
      const float* __restrict__ gg, const float* __restrict__ bb, float* __restrict__ out){
  const int bz = blockIdx.y;
  const int oy0 = blockIdx.x*16;
  const int c = bz & 127;
  __shared__ float xs[23][136];
  __shared__ float wsm[64];
  const int t = threadIdx.x;
  if (t < 64) wsm[t] = dw[c*64 + t];
  for (int i = t; i < 23*135; i += 256){
    int py = i / 135, px = i - py*135;
    int gy = oy0 + py - 3, gx = px - 3;
    float v = 0.f;
    if (gy >= 0 && gy <= 128 && gx >= 0 && gx <= 128){
      int yy = (gy==128)?126:gy, xx = (gx==128)?126:gx;
      v = comb[((size_t)bz*128 + yy)*128 + xx];
    }
    xs[py][px] = v;
  }
  __syncthreads();
  const int tx = t & 31, ty = t >> 5;
  const int x0 = tx*4, y0 = ty*2;
  float acc[2][4] = {};
  #pragma unroll
  for (int iy = 0; iy < 9; ++iy){
    float row[12];
    *(float4*)&row[0] = *(const float4*)&xs[y0+iy][x0];
    *(float4*)&row[4] = *(const float4*)&xs[y0+iy][x0+4];
    *(float4*)&row[8] = *(const float4*)&xs[y0+iy][x0+8];
    #pragma unroll
    for (int dy = 0; dy < 2; ++dy){
      const int ky = iy - dy;
      if (ky < 0 || ky > 7) continue;
      #pragma unroll
      for (int kx = 0; kx < 8; ++kx){
        float wv = wsm[ky*8 + kx];
        #pragma unroll
        for (int dx = 0; dx < 4; ++dx)
          acc[dy][dx] += wv * row[dx + kx];
      }
    }
  }
  float g = gg[c], bi = bb[c];
  #pragma unroll
  for (int dy = 0; dy < 2; ++dy){
    float4 o4;
    o4.x = acc[dy][0]*g + bi;
    o4.y = acc[dy][1]*g + bi;
    o4.z = acc[dy][2]*g + bi;
    o4.w = acc[dy][3]*g + bi;
    *(float4*)&out[((size_t)bz*128 + oy0 + y0 + dy)*128 + x0] = o4;
  }
}

// ============ P7: zero omT halo cols ============
__global__ void k_omzero(short* __restrict__ omT){
  int t = blockIdx.x*256 + threadIdx.x;
  int ci = t & 127, side = (t >> 7) & 1, row = t >> 8;
  int cpad = side ? 129 : 0;
  omT[((size_t)row*130 + cpad)*128 + ci] = 0;
}

// ============ P8: repack up_w -> wup[tap][co][ci] bf16 ============
__global__ __launch_bounds__(256) void k_uwrep(const float* __restrict__ w, short* __restrict__ wup){
  int i = blockIdx.x*256 + threadIdx.x;
  int ci = i & 127, co = (i >> 7) & 63, tap = i >> 13;
  wup[i] = f2bs(w[(co*128 + ci)*9 + tap]);
}

// ============ K11: 1x1 proj conv 128->128 -> omT bf16 NHWC+halo ============
__global__ __launch_bounds__(256) void k_pw(const float* __restrict__ p1, const float* __restrict__ w,
      short* __restrict__ omT){
  const int pt = blockIdx.x, cb = blockIdx.y;
  const int P0 = pt*64; const int b = P0 >> 14; const int rem0 = P0 & 16383;
  const int y = rem0 >> 7, x0 = rem0 & 127;
  __shared__ float xsm[128][65];
  __shared__ float wsm[64][129];
  const int tx = threadIdx.x, ty = threadIdx.y, t = ty*16+tx;
  for (int i = t; i < 128*64; i += 256){
    int ci = i >> 6, p = i & 63;
    xsm[ci][p] = p1[(size_t)(b*128+ci)*16384 + rem0 + p];
  }
  for (int i = t; i < 64*128; i += 256){
    int co = i >> 7, ci = i & 127;
    wsm[co][ci] = w[(cb*64+co)*128 + ci];
  }
  __syncthreads();
  float acc[4][4] = {};
  for (int ci = 0; ci < 128; ++ci){
    float hv[4], wv[4];
    #pragma unroll
    for (int jj = 0; jj < 4; ++jj) hv[jj] = xsm[ci][jj*16+tx];
    #pragma unroll
    for (int ii = 0; ii < 4; ++ii) wv[ii] = wsm[ii*16+ty][ci];
    #pragma unroll
    for (int ii = 0; ii < 4; ++ii)
      #pragma unroll
      for (int jj = 0; jj < 4; ++jj) acc[ii][jj] += wv[ii]*hv[jj];
  }
  __syncthreads();
  float* pt_t = &xsm[0][0];
  #pragma unroll
  for (int ii = 0; ii < 4; ++ii)
    #pragma unroll
    for (int jj = 0; jj < 4; ++jj)
      pt_t[(jj*16+tx)*65 + ii*16+ty] = acc[ii][jj];
  __syncthreads();
  for (int i = t; i < 4096; i += 256){
    int px = i >> 6, co_l = i & 63;
    omT[((size_t)(b*128 + y)*130 + x0 + px + 1)*128 + cb*64 + co_l] = f2bs(pt_t[px*65 + co_l]);
  }
}

// ============ K12: transposed 3x3 stride-2 conv 128->64 (MFMA, parity decomp) ============
__global__ __launch_bounds__(256) void k_upm(const short* __restrict__ omT, const short* __restrict__ wup,
      float* __restrict__ out){
  int blk = blockIdx.x;
  blk = (blk & 7)*64 + (blk >> 3);           // XCD swizzle (grid 512)
  const int b = blk >> 7, y = blk & 127;
  const int t = threadIdx.x, lane = t & 63, wave = t >> 6;
  const int quad = lane >> 4, l15 = lane & 15;
  const int m0w = wave*32;
  __shared__ __align__(16) char smem[53504];
  short* asp = (short*)smem;
  short* bsp = (short*)(smem + 16640);
  float* ptile = (float*)smem;
  const int PAR[9] = {3,2,3, 1,0,1, 3,2,3};
  const int ROW[9] = {0,0,0, 0,0,0, 1,1,1};
  const int SHF[9] = {0,0,1, 0,0,1, 0,0,1};
  f32x4 acc[4][2][4];
  #pragma unroll
  for (int p = 0; p < 4; ++p)
    #pragma unroll
    for (int mt = 0; mt < 2; ++mt)
      #pragma unroll
      for (int nt = 0; nt < 4; ++nt) acc[p][mt][nt] = (f32x4){0.f,0.f,0.f,0.f};
  for (int ch = 0; ch < 4; ++ch){
    const int ci0 = ch*32;
    __syncthreads();
    for (int i = t; i < 1040; i += 256){
      int rw = (i >= 520), j = i - rw*520;
      int col = j >> 2, cq = j & 3;
      int row = rw*130 + col;
      uint4 val = {0,0,0,0};
      if (y + rw < 128)
        val = *(const uint4*)&omT[((size_t)(b*128 + y + rw)*130 + col)*128 + ci0 + cq*8];
      *(uint4*)&asp[(row*4 + SLOT(row,cq))*8] = val;
    }
    for (int i = t; i < 2304; i += 256){
      int rr = i >> 2, cq = i & 3;
      *(uint4*)&bsp[(rr*4 + SLOT(rr,cq))*8] = *(const uint4*)&wup[rr*128 + ci0 + cq*8];
    }
    __syncthreads();
    #pragma unroll
    for (int k = 0; k < 9; ++k){
      const int pr = PAR[k], rw = ROW[k], sh = SHF[k];
      if (rw && y == 127) continue;
      short8 af[2], bf[4];
      #pragma unroll
      for (int mt = 0; mt < 2; ++mt){
        int row = rw*130 + m0w + mt*16 + l15 + 1 + sh;
        af[mt] = *(const short8*)&asp[(row*4 + SLOT(row,quad))*8];
      }
      #pragma unroll
      for (int nt = 0; nt < 4; ++nt){
        int row = k*64 + nt*16 + l15;
        bf[nt] = *(const short8*)&bsp[(row*4 + SLOT(row,quad))*8];
      }
      #pragma unroll
      for (int mt = 0; mt < 2; ++mt)
        #pragma unroll
        for (int nt = 0; nt < 4; ++nt)
          acc[pr][mt][nt] = __builtin_amdgcn_mfma_f32_16x16x32_bf16(af[mt], bf[nt], acc[pr][mt][nt], 0, 0, 0);
    }
  }
  #pragma unroll
  for (int p = 0; p < 4; ++p){
    __syncthreads();
    #pragma unroll
    for (int mt = 0; mt < 2; ++mt)
      #pragma unroll
      for (int nt = 0; nt < 4; ++nt){
        int co = nt*16 + l15;
        int xb = m0w + mt*16 + quad*4;
        #pragma unroll
        for (int r = 0; r < 4; ++r)
          ptile[co*132 + xb + r] = acc[p][mt][nt][r];
      }
    __syncthreads();
    int py = p >> 1, px = p & 1;
    int Y = 2*y + py;
    for (int i = t; i < 8192; i += 256){
      int co = i >> 7, xx = i & 127;
      out[((size_t)(b*64 + co)*256 + Y)*256 + 2*xx + px] = ptile[co*132 + xx];
    }
  }
}

extern "C" void kernel_launch(void* const* d_in, const int* in_sizes, int n_in,
                              void* d_out, int out_size, void* d_ws, size_t ws_size,
                              hipStream_t stream) {
  const float* x       = (const float*)d_in[0];
  const float* conv_w  = (const float*)d_in[1];
  const float* bn1_g   = (const float*)d_in[2];
  const float* bn1_b   = (const float*)d_in[3];
  const float* qkv_w   = (const float*)d_in[4];
  const float* loc1_w  = (const float*)d_in[5];
  const float* loc1_g  = (const float*)d_in[6];
  const float* loc1_b  = (const float*)d_in[7];
  const float* loc2_w  = (const float*)d_in[8];
  const float* loc2_g  = (const float*)d_in[9];
  const float* loc2_b  = (const float*)d_in[10];
  const float* rel_t   = (const float*)d_in[11];
  const float* cw_w    = (const float*)d_in[12];
  const float* cw_g    = (const float*)d_in[13];
  const float* cw_b    = (const float*)d_in[14];
  const float* hc_w    = (const float*)d_in[15];
  const float* hc_g    = (const float*)d_in[16];
  const float* hc_b    = (const float*)d_in[17];
  const float* hw_w    = (const float*)d_in[18];
  const float* hw_g    = (const float*)d_in[19];
  const float* hw_b    = (const float*)d_in[20];
  const float* proj_dw = (const float*)d_in[21];
  const float* proj_g  = (const float*)d_in[22];
  const float* proj_b  = (const float*)d_in[23];
  const float* proj_pw = (const float*)d_in[24];
  const float* up_w    = (const float*)d_in[25];

  char* ws = (char*)d_ws;
  float* local  = (float*)(ws + OFF_LOCAL);
  bf16*  q      = (bf16*)(ws + OFF_Q);
  bf16*  k      = (bf16*)(ws + OFF_K);
  bf16*  v      = (bf16*)(ws + OFF_V);
  bf16*  dots   = (bf16*)(ws + OFF_DOTS);
  bf16*  z1     = (bf16*)(ws + OFF_Z1);
  bf16*  z2     = (bf16*)(ws + OFF_Z2);
  bf16*  z3     = (bf16*)(ws + OFF_Z3);
  float* G1     = (float*)(ws + OFF_G1);
  float* G2     = (float*)(ws + OFF_G2);
  float* G3     = (float*)(ws + OFF_G3);
  short* xT     = (short*)(ws + OFF_DOTS);
  short* hT     = (short*)(ws + OFF_HT);
  short* w2bf   = (short*)(ws + OFF_Z1);
  short* wloc   = (short*)(ws + OFF_Z2);
  short* wqkv   = (short*)(ws + OFF_Z3);
  short* omT    = (short*)(ws + OFF_DOTS);
  short* wup    = (short*)(ws + OFF_Z1);
  float* o_img  = (float*)(ws + OFF_Q);
  float* Fh     = (float*)(ws + OFF_DOTS);
  float* Fw     = (float*)(ws + OFF_DOTS + 8388608);
  float* comb   = (float*)(ws + OFF_H);
  float* proj1  = (float*)(ws + OFF_LOCAL);
  float* outp   = (float*)d_out;

  dim3 blk2(16,16);
  k_wrep <<<1152, 256, 0, stream>>>(conv_w, w2bf);
  k_xzero<<<1024, 256, 0, stream>>>(xT);
  k_xrep <<<8192, 256, 0, stream>>>(x, xT);
  k_hzero<<<512, 256, 0, stream>>>(hT);
  k_conv1m<<<1024, 256, 0, stream>>>(xT, w2bf, bn1_g, bn1_b, hT);
  k_lwrep<<<576, 256, 0, stream>>>(loc1_w, loc1_g, loc2_w, loc2_g, wloc);
  k_localm<<<1024, 256, 0, stream>>>(hT, wloc, loc1_b, loc2_b, local);
  k_wqkvrep<<<192, 256, 0, stream>>>(qkv_w, wqkv);
  k_qkvm <<<dim3(512,3), 256, 0, stream>>>(hT, wqkv, q, k, v);
  k_dots <<<dim3(NWIN,8), 256, 0, stream>>>(q, k, rel_t, dots);
  k_zall <<<NWIN, 256, 0, stream>>>(dots, z1, z2, z3);
  k_gate <<<dim3(NWIN,2),  256, 0, stream>>>(z1, cw_w, cw_g, cw_b, G1, 8, 64);
  k_gate <<<dim3(NWIN,2),  256, 0, stream>>>(z2, hc_w, hc_g, hc_b, G2, 64, 8);
  k_gate3<<<NWIN, 256, 0, stream>>>(z3, hw_w, hw_g, hw_b, G3);
  k_attn <<<dim3(NWIN,8), 256, 0, stream>>>(dots, G1, G2, G3, v, o_img);
  k_fw   <<<8192, 256, 0, stream>>>(o_img, Fw);
  k_fh   <<<8192, 256, 0, stream>>>(o_img, Fh);
  k_comb <<<512, 256, 0, stream>>>(o_img, Fh, Fw, local, comb);
  k_dw   <<<dim3(8, BB*128), 256, 0, stream>>>(comb, proj_dw, proj_g, proj_b, proj1);
  k_omzero<<<512, 256, 0, stream>>>(omT);
  k_uwrep<<<288, 256, 0, stream>>>(up_w, wup);
  k_pw   <<<dim3(1024,2), blk2, 0, stream>>>(proj1, proj_pw, omT);
  k_upm  <<<512, 256, 0, stream>>>(omT, wup, outp);
}

// Round 8
// 612.663 us; speedup vs baseline: 1.1317x; 1.0340x over previous
//
#include <hip/hip_runtime.h>
#include <hip/hip_bf16.h>

typedef __hip_bfloat16 bf16;
typedef __attribute__((ext_vector_type(8))) short short8;
typedef __attribute__((ext_vector_type(4))) float f32x4;

#define DEV __device__ __forceinline__
DEV float b2f(bf16 v){ return __bfloat162float(v); }
DEV bf16 f2b(float v){ return __float2bfloat16(v); }
DEV short f2bs(float v){ union{ bf16 b; short s; } u; u.b = __float2bfloat16(v); return u.s; }
DEV float s2f(short s){ union{ short s; bf16 b; } u; u.s = s; return __bfloat162float(u.b); }
DEV float sigm(float x){ return 1.f/(1.f + expf(-x)); }

// ---- problem constants ----
#define BB 4
#define CIN 256
#define MID 128
#define COUT 64
#define HH 128
#define WW 128
#define WS 8
#define HEADS 8
#define HD 16
#define NTOK 64
#define NWIN 1024

// LDS slot swizzle: row-major 64B rows, slot = cq ^ ((row>>1)&3)
#define SLOT(row,cq) ((cq) ^ (((row)>>1)&3))

// ---- workspace layout (bytes) ----
static const size_t OFF_H     = 0;
static const size_t OFF_LOCAL = 33554432;
static const size_t OFF_Q     = 67108864;
static const size_t OFF_K     = 83886080;
static const size_t OFF_V     = 100663296;
static const size_t OFF_DOTS  = 117440512;
static const size_t OFF_Z1    = 184549376;
static const size_t OFF_Z2    = 186646528;
static const size_t OFF_Z3    = 188743680;
static const size_t OFF_G1    = 205520896;
static const size_t OFF_G2    = 207618048;
static const size_t OFF_G3    = 209715200;
static const size_t OFF_HT    = OFF_DOTS + 34078720;

// ============ P1: repack conv_w -> w2[kk][co][ci] bf16 ============
__global__ __launch_bounds__(256) void k_wrep(const float* __restrict__ w, short* __restrict__ w2){
  int i = blockIdx.x*256 + threadIdx.x;
  int ci = i & 255, co = (i >> 8) & 127, kk = i >> 15;
  w2[i] = f2bs(w[(co*256 + ci)*9 + kk]);
}

// ============ P2: zero pad columns of xT ============
__global__ void k_xzero(short* __restrict__ xT){
  int t = blockIdx.x*256 + threadIdx.x;
  int ci = t & 255, side = (t >> 8) & 1, row = t >> 9;
  int cpad = side ? 129 : 0;
  xT[((size_t)row*130 + cpad)*256 + ci] = 0;
}

// ============ P3: x NCHW fp32 -> xT[b][r][c+1][ci] bf16 ============
__global__ __launch_bounds__(256) void k_xrep(const float* __restrict__ x, short* __restrict__ xT){
  const int blk = blockIdx.x;
  const int cgrp = blk & 1, cig = (blk >> 1) & 7, r = (blk >> 4) & 127, b = blk >> 11;
  const int c0 = cgrp*64, ci0 = cig*32;
  __shared__ float lds[32][65];
  const int t = threadIdx.x;
  for (int i = t; i < 2048; i += 256){
    int lci = i >> 6, c = i & 63;
    lds[lci][c] = x[((size_t)(b*256 + ci0 + lci)*128 + r)*128 + c0 + c];
  }
  __syncthreads();
  for (int i = t; i < 2048; i += 256){
    int lci = i & 31, cc = i >> 5;
    xT[((size_t)(b*128 + r)*130 + c0 + cc + 1)*256 + ci0 + lci] = f2bs(lds[lci][cc]);
  }
}

// ============ K1: conv3x3 256->128 + bn + relu -> hT bf16 ============
// 1-row co-split blocks (grid 1024, high occupancy) + SLOT-swizzled LDS (conflict-free).
__global__ __launch_bounds__(256) void k_conv1m(const short* __restrict__ xT, const short* __restrict__ w2,
      const float* __restrict__ gg, const float* __restrict__ bb, short* __restrict__ hT){
  int blk = blockIdx.x;
  blk = (blk & 7)*128 + (blk >> 3);          // XCD swizzle (grid 1024)
  const int cg = blk & 1, y = (blk >> 1) & 127, b = blk >> 8;
  const int t = threadIdx.x, lane = t & 63, wave = t >> 6;
  const int quad = lane >> 4, l15 = lane & 15;
  const int m0 = wave*32;
  __shared__ __align__(16) short smem[10304];   // as 130*32 + bs 192*32
  short* as = smem;           // (col*4 + SLOT(col,cq))*8
  short* bs = smem + 4160;    // (rr*4 + SLOT(rr,cq))*8, rr = kx*64+co_l
  f32x4 acc[2][4];
  #pragma unroll
  for (int i = 0; i < 2; ++i)
    #pragma unroll
    for (int j = 0; j < 4; ++j) acc[i][j] = (f32x4){0.f,0.f,0.f,0.f};
  for (int ky = 0; ky < 3; ++ky){
    int r = y + ky - 1;
    if ((unsigned)r >= 128u) continue;
    const short* xrow = xT + (size_t)(b*128 + r)*130*256;
    const short* wk   = w2 + (size_t)(ky*384 + cg*64)*256;
    for (int ch = 0; ch < 8; ++ch){
      const int ci0 = ch*32;
      __syncthreads();
      for (int i = t; i < 520; i += 256){
        int col = i >> 2, cq = i & 3;
        *(uint4*)&as[(col*4 + SLOT(col,cq))*8] = *(const uint4*)&xrow[col*256 + ci0 + cq*8];
      }
      for (int i = t; i < 768; i += 256){
        int rr = i >> 2, cq = i & 3;
        *(uint4*)&bs[(rr*4 + SLOT(rr,cq))*8] =
          *(const uint4*)&wk[(((rr >> 6)<<7) + (rr & 63))*256 + ci0 + cq*8];
      }
      __syncthreads();
      #pragma unroll
      for (int kx = 0; kx < 3; ++kx){
        short8 af[2], bf[4];
        #pragma unroll
        for (int mt = 0; mt < 2; ++mt){
          int col = m0 + mt*16 + l15 + kx;
          af[mt] = *(const short8*)&as[(col*4 + SLOT(col,quad))*8];
        }
        #pragma unroll
        for (int nt = 0; nt < 4; ++nt){
          int rr = kx*64 + nt*16 + l15;
          bf[nt] = *(const short8*)&bs[(rr*4 + SLOT(rr,quad))*8];
        }
        #pragma unroll
        for (int mt = 0; mt < 2; ++mt)
          #pragma unroll
          for (int nt = 0; nt < 4; ++nt)
            acc[mt][nt] = __builtin_amdgcn_mfma_f32_16x16x32_bf16(af[mt], bf[nt], acc[mt][nt], 0, 0, 0);
      }
    }
  }
  // epilogue: bn+relu, transpose via LDS, write bf16 NHWC rows of hT
  __syncthreads();
  short* tb = smem;   // [128][72] bf16 (x, co_local)
  #pragma unroll
  for (int nt = 0; nt < 4; ++nt){
    int cl = nt*16 + l15, co = cg*64 + cl;
    float g = gg[co], bia = bb[co];
    #pragma unroll
    for (int mt = 0; mt < 2; ++mt){
      int xb = m0 + mt*16 + quad*4;
      #pragma unroll
      for (int r2 = 0; r2 < 4; ++r2)
        tb[(xb + r2)*72 + cl] = f2bs(fmaxf(acc[mt][nt][r2]*g + bia, 0.f));
    }
  }
  __syncthreads();
  for (int i = t; i < 1024; i += 256){
    int xx = i >> 3, c8 = i & 7;
    *(uint4*)&hT[((size_t)(b*128 + y)*130 + xx + 1)*128 + cg*64 + c8*8] = *(const uint4*)&tb[xx*72 + c8*8];
  }
}

// ============ P4: zero pad columns of hT ============
__global__ void k_hzero(short* __restrict__ hT){
  int t = blockIdx.x*256 + threadIdx.x;
  int ci = t & 127, side = (t >> 7) & 1, row = t >> 8;
  int cpad = side ? 129 : 0;
  hT[((size_t)row*130 + cpad)*128 + ci] = 0;
}

// ============ P6: fold local weights: wloc[kk][co][ci] bf16 ============
__global__ __launch_bounds__(256) void k_lwrep(const float* __restrict__ w1, const float* __restrict__ g1,
      const float* __restrict__ w2, const float* __restrict__ g2, short* __restrict__ wloc){
  int i = blockIdx.x*256 + threadIdx.x;
  int ci = i & 127, row = (i >> 7) % 384, ky = i / 49152;
  int kx = row >> 7, co = row & 127;
  float v = w1[(co*128 + ci)*9 + ky*3 + kx] * g1[co];
  if (ky == 1 && kx == 1) v += w2[co*128 + ci] * g2[co];
  wloc[i] = f2bs(v);
}

// ============ K2: local conv (folded 3x3+1x1), 1-row blocks, SLOT LDS ============
__global__ __launch_bounds__(256) void k_localm(const short* __restrict__ hT, const short* __restrict__ wloc,
      const float* __restrict__ b1, const float* __restrict__ b2, float* __restrict__ out){
  int blk = blockIdx.x;
  blk = (blk & 7)*128 + (blk >> 3);          // XCD swizzle (grid 1024)
  const int cg = blk & 1, y = (blk >> 1) & 127, b = blk >> 8;
  const int t = threadIdx.x, lane = t & 63, wave = t >> 6;
  const int quad = lane >> 4, l15 = lane & 15;
  const int m0 = wave*32;
  __shared__ __align__(16) short smem2[10304];
  short* as = smem2;
  short* bs = smem2 + 4160;
  f32x4 acc[2][4];
  #pragma unroll
  for (int i = 0; i < 2; ++i)
    #pragma unroll
    for (int j = 0; j < 4; ++j) acc[i][j] = (f32x4){0.f,0.f,0.f,0.f};
  for (int ky = 0; ky < 3; ++ky){
    int r = y + ky - 1;
    if ((unsigned)r >= 128u) continue;
    const short* xrow = hT + (size_t)(b*128 + r)*130*128;
    const short* wk   = wloc + (size_t)(ky*384 + cg*64)*128;
    for (int ch = 0; ch < 4; ++ch){
      const int ci0 = ch*32;
      __syncthreads();
      for (int i = t; i < 520; i += 256){
        int col = i >> 2, cq = i & 3;
        *(uint4*)&as[(col*4 + SLOT(col,cq))*8] = *(const uint4*)&xrow[col*128 + ci0 + cq*8];
      }
      for (int i = t; i < 768; i += 256){
        int rr = i >> 2, cq = i & 3;
        *(uint4*)&bs[(rr*4 + SLOT(rr,cq))*8] =
          *(const uint4*)&wk[(((rr >> 6)<<7) + (rr & 63))*128 + ci0 + cq*8];
      }
      __syncthreads();
      #pragma unroll
      for (int kx = 0; kx < 3; ++kx){
        short8 af[2], bf[4];
        #pragma unroll
        for (int mt = 0; mt < 2; ++mt){
          int col = m0 + mt*16 + l15 + kx;
          af[mt] = *(const short8*)&as[(col*4 + SLOT(col,quad))*8];
        }
        #pragma unroll
        for (int nt = 0; nt < 4; ++nt){
          int rr = kx*64 + nt*16 + l15;
          bf[nt] = *(const short8*)&bs[(rr*4 + SLOT(rr,quad))*8];
        }
        #pragma unroll
        for (int mt = 0; mt < 2; ++mt)
          #pragma unroll
          for (int nt = 0; nt < 4; ++nt)
            acc[mt][nt] = __builtin_amdgcn_mfma_f32_16x16x32_bf16(af[mt], bf[nt], acc[mt][nt], 0, 0, 0);
      }
    }
  }
  #pragma unroll
  for (int nt = 0; nt < 4; ++nt){
    int co = cg*64 + nt*16 + l15;
    float bia = b1[co] + b2[co];
    #pragma unroll
    for (int mt = 0; mt < 2; ++mt){
      int xb = m0 + mt*16 + quad*4;
      float4 o4;
      o4.x = acc[mt][nt][0] + bia;
      o4.y = acc[mt][nt][1] + bia;
      o4.z = acc[mt][nt][2] + bia;
      o4.w = acc[mt][nt][3] + bia;
      *(float4*)&out[((size_t)(b*128 + co)*128 + y)*128 + xb] = o4;
    }
  }
}

// ============ P9: qkv_w fp32 -> bf16 [oc][ci] ============
__global__ __launch_bounds__(256) void k_wqkvrep(const float* __restrict__ w, short* __restrict__ wqkv){
  int i = blockIdx.x*256 + threadIdx.x;
  wqkv[i] = f2bs(w[i]);
}

// ============ K3: qkv 1x1 conv (MFMA GEMM over hT) -> windowed q,k,v ============
__global__ __launch_bounds__(256) void k_qkvm(const short* __restrict__ hT, const short* __restrict__ wqkv,
      bf16* __restrict__ q, bf16* __restrict__ k, bf16* __restrict__ v){
  const int blk = blockIdx.x, ocg = blockIdx.y;
  const int b = blk >> 7, y = blk & 127;
  const int t = threadIdx.x, lane = t & 63, wave = t >> 6;
  const int quad = lane >> 4, l15 = lane & 15;
  const int m0 = (wave >> 1)*64, n0 = (wave & 1)*64;
  __shared__ __align__(16) short asq[4096];   // (col*4 + SLOT(col,cq))*8
  __shared__ __align__(16) short bsq[4096];
  const short* xrow = hT + ((size_t)(b*128 + y)*130 + 1)*128;
  const short* wk   = wqkv + (size_t)ocg*128*128;
  f32x4 acc[4][4];
  #pragma unroll
  for (int i = 0; i < 4; ++i)
    #pragma unroll
    for (int j = 0; j < 4; ++j) acc[i][j] = (f32x4){0.f,0.f,0.f,0.f};
  for (int ch = 0; ch < 4; ++ch){
    const int ci0 = ch*32;
    __syncthreads();
    for (int i = t; i < 512; i += 256){
      int col = i >> 2, cq = i & 3;
      *(uint4*)&asq[(col*4 + SLOT(col,cq))*8] = *(const uint4*)&xrow[col*128 + ci0 + cq*8];
    }
    for (int i = t; i < 512; i += 256){
      int rr = i >> 2, cq = i & 3;
      *(uint4*)&bsq[(rr*4 + SLOT(rr,cq))*8] = *(const uint4*)&wk[rr*128 + ci0 + cq*8];
    }
    __syncthreads();
    short8 af[4], bf[4];
    #pragma unroll
    for (int mt = 0; mt < 4; ++mt){
      int row = m0 + mt*16 + l15;
      af[mt] = *(const short8*)&asq[(row*4 + SLOT(row,quad))*8];
    }
    #pragma unroll
    for (int nt = 0; nt < 4; ++nt){
      int row = n0 + nt*16 + l15;
      bf[nt] = *(const short8*)&bsq[(row*4 + SLOT(row,quad))*8];
    }
    #pragma unroll
    for (int mt = 0; mt < 4; ++mt)
      #pragma unroll
      for (int nt = 0; nt < 4; ++nt)
        acc[mt][nt] = __builtin_amdgcn_mfma_f32_16x16x32_bf16(af[mt], bf[nt], acc[mt][nt], 0, 0, 0);
  }
  bf16* dst = (ocg == 0) ? q : (ocg == 1) ? k : v;
  const int iy = y & 7, hy = y >> 3;
  #pragma unroll
  for (int nt = 0; nt < 4; ++nt){
    int co = n0 + nt*16 + l15;
    int head = co >> 4, d = co & 15;
    #pragma unroll
    for (int mt = 0; mt < 4; ++mt){
      int xb = m0 + mt*16 + quad*4;
      #pragma unroll
      for (int rr = 0; rr < 4; ++rr){
        int x = xb + rr;
        int bw = b*256 + hy*16 + (x >> 3);
        int n = iy*8 + (x & 7);
        dst[((size_t)(bw*8+head)*64 + n)*16 + d] = f2b(acc[mt][nt][rr]);
      }
    }
  }
}

// ============ K4: dots = q.k^T * 0.25 + relpos bias (vectorized) ============
__global__ __launch_bounds__(256) void k_dots(const bf16* __restrict__ q, const bf16* __restrict__ kk,
      const float* __restrict__ rel, bf16* __restrict__ dots){
  const int bw = blockIdx.x, hd = blockIdx.y;
  __shared__ __align__(16) short qs[64][16];
  __shared__ __align__(16) short ks2[64][16];   // octet s of row m at [(s^((m>>4)&1))*8]
  const int t = threadIdx.x;
  const size_t base = (size_t)(bw*8+hd)*1024;
  const short* qp = (const short*)q;
  const short* kp = (const short*)kk;
  if (t < 64){
    *(uint4*)&qs[t][0] = *(const uint4*)&qp[base + t*16];
    *(uint4*)&qs[t][8] = *(const uint4*)&qp[base + t*16 + 8];
  } else if (t < 128){
    int r = t - 64;
    uint4 a0 = *(const uint4*)&kp[base + r*16];
    uint4 a1 = *(const uint4*)&kp[base + r*16 + 8];
    int p = (r >> 4) & 1;
    *(uint4*)&ks2[r][p*8]     = a0;
    *(uint4*)&ks2[r][8 - p*8] = a1;
  }
  __syncthreads();
  const int n = t >> 2, jm = t & 3;
  float qr[16];
  short8 q0 = *(const short8*)&qs[n][0];
  short8 q1 = *(const short8*)&qs[n][8];
  #pragma unroll
  for (int d = 0; d < 8; ++d){ qr[d] = s2f(q0[d]); qr[8+d] = s2f(q1[d]); }
  const int ny = n >> 3, nx = n & 7;
  float a[16];
  #pragma unroll
  for (int mm = 0; mm < 16; ++mm){
    int m = jm*16 + mm;
    int p = (m >> 4) & 1;
    short8 k0 = *(const short8*)&ks2[m][p*8];
    short8 k1 = *(const short8*)&ks2[m][8 - p*8];
    float acc = 0.f;
    #pragma unroll
    for (int d = 0; d < 8; ++d) acc += qr[d]*s2f(k0[d]);
    #pragma unroll
    for (int d = 0; d < 8; ++d) acc += qr[8+d]*s2f(k1[d]);
    int my = m >> 3, mx = m & 7;
    int ridx = (ny - my + 7)*15 + (nx - mx + 7);
    a[mm] = acc*0.25f + rel[ridx*8 + hd];
  }
  short8 s0, s1;
  #pragma unroll
  for (int j = 0; j < 8; ++j){ s0[j] = f2bs(a[j]); s1[j] = f2bs(a[8+j]); }
  short* dp = (short*)dots + base*4 + (size_t)n*64 + jm*16;
  *(short8*)&dp[0] = s0;
  *(short8*)&dp[8] = s1;
}

// ============ K5: fused axis reductions (z1 + z2 + z3 in one pass) ============
__global__ __launch_bounds__(256) void k_zall(const bf16* __restrict__ dots,
      bf16* __restrict__ z1, bf16* __restrict__ z2, bf16* __restrict__ z3){
  const int bw = blockIdx.x;
  const int t = threadIdx.x;
  const int q4 = t >> 2, j4 = t & 3;
  __shared__ float sd[64][65];
  float mx3[16], sm3[16];
  #pragma unroll
  for (int i = 0; i < 16; ++i){ mx3[i] = -1e30f; sm3[i] = 0.f; }
  const short* dp = (const short*)dots + (size_t)bw*32768;
  for (int hd = 0; hd < 8; ++hd){
    __syncthreads();
    const short* p = dp + (size_t)hd*4096;
    #pragma unroll
    for (int g = 0; g < 2; ++g){
      short8 s8 = *(const short8*)&p[t*16 + g*8];
      #pragma unroll
      for (int j = 0; j < 8; ++j){
        float vv = s2f(s8[j]);
        sd[q4][j4*16 + g*8 + j] = vv;
        mx3[g*8+j] = fmaxf(mx3[g*8+j], vv);
        sm3[g*8+j] += vv;
      }
    }
    __syncthreads();
    float mx = -1e30f, sm = 0.f;
    #pragma unroll
    for (int m = 0; m < 16; ++m){
      float vv = sd[q4][j4*16 + m];
      mx = fmaxf(mx, vv); sm += vv;
    }
    mx = fmaxf(mx, __shfl_xor(mx, 1, 4));
    mx = fmaxf(mx, __shfl_xor(mx, 2, 4));
    sm += __shfl_xor(sm, 1, 4);
    sm += __shfl_xor(sm, 2, 4);
    if (j4 == 0){
      z2[(size_t)bw*1024 + q4*8 + hd]       = f2b(mx);
      z2[(size_t)bw*1024 + 512 + q4*8 + hd] = f2b(sm*(1.f/64.f));
    }
    float mxc = -1e30f, smc = 0.f;
    #pragma unroll
    for (int nn = 0; nn < 16; ++nn){
      float vv = sd[j4*16 + nn][q4];
      mxc = fmaxf(mxc, vv); smc += vv;
    }
    mxc = fmaxf(mxc, __shfl_xor(mxc, 1, 4));
    mxc = fmaxf(mxc, __shfl_xor(mxc, 2, 4));
    smc += __shfl_xor(smc, 1, 4);
    smc += __shfl_xor(smc, 2, 4);
    if (j4 == 0){
      z1[(size_t)bw*1024 + hd*64 + q4]       = f2b(mxc);
      z1[(size_t)bw*1024 + 512 + hd*64 + q4] = f2b(smc*(1.f/64.f));
    }
  }
  short* zp = (short*)z3 + (size_t)bw*8192;
  short8 o0, o1, p0, p1;
  #pragma unroll
  for (int j = 0; j < 8; ++j){
    o0[j] = f2bs(mx3[j]);        o1[j] = f2bs(mx3[8+j]);
    p0[j] = f2bs(sm3[j]*0.125f); p1[j] = f2bs(sm3[8+j]*0.125f);
  }
  *(short8*)&zp[t*16]          = o0;
  *(short8*)&zp[t*16 + 8]      = o1;
  *(short8*)&zp[4096 + t*16]   = p0;
  *(short8*)&zp[4096 + t*16+8] = p1;
}

// ============ K6: generic 7x7 2->1 conv + bn + sigmoid (small gates) ============
__global__ __launch_bounds__(256) void k_gate(const bf16* __restrict__ z, const float* __restrict__ w,
      const float* __restrict__ gg, const float* __restrict__ bb, float* __restrict__ G, int R, int C){
  __shared__ float wsm[98];
  const int t = threadIdx.x;
  if (t < 98) wsm[t] = w[t];
  __syncthreads();
  const int bw = blockIdx.x;
  int p = blockIdx.y*256 + t; if (p >= R*C) return;
  int y = p / C, x = p - y*C;
  float acc = 0.f;
  for (int c = 0; c < 2; ++c)
    for (int ky = 0; ky < 7; ++ky){
      int iy = y + ky - 3; if ((unsigned)iy >= (unsigned)R) continue;
      for (int kx = 0; kx < 7; ++kx){
        int ix = x + kx - 3; if ((unsigned)ix >= (unsigned)C) continue;
        acc += b2f(z[((size_t)(bw*2+c)*R + iy)*C + ix]) * wsm[c*49 + ky*7 + kx];
      }
    }
  G[(size_t)bw*R*C + p] = sigm(acc*gg[0] + bb[0]);
}

// ============ K6b: specialized 64x64 gate (G3) ============
__global__ __launch_bounds__(256) void k_gate3(const bf16* __restrict__ z, const float* __restrict__ w,
      const float* __restrict__ gg, const float* __restrict__ bb, float* __restrict__ G){
  const int bw = blockIdx.x;
  __shared__ float pad[2][70][72];
  __shared__ float wsm[98];
  const int t = threadIdx.x;
  if (t < 98) wsm[t] = w[t];
  for (int i = t; i < 2*70*70; i += 256){
    int c = i / 4900, r = i % 4900;
    int py = r / 70, px = r % 70;
    int y = py - 3, x = px - 3;
    float v = 0.f;
    if ((unsigned)y < 64u && (unsigned)x < 64u)
      v = b2f(z[(size_t)bw*8192 + c*4096 + y*64 + x]);
    pad[c][py][px] = v;
  }
  __syncthreads();
  const int tx = t & 15, ty = t >> 4;
  const int x0 = tx*4, y0 = ty*4;
  float acc[4][4] = {};
  #pragma unroll
  for (int c = 0; c < 2; ++c){
    float wr[49];
    #pragma unroll
    for (int kk = 0; kk < 49; ++kk) wr[kk] = wsm[c*49 + kk];
    #pragma unroll
    for (int iy = 0; iy < 10; ++iy){
      float row[10];
      #pragma unroll
      for (int j = 0; j < 10; ++j) row[j] = pad[c][y0+iy][x0+j];
      #pragma unroll
      for (int dy = 0; dy < 4; ++dy){
        const int ky = iy - dy;
        if (ky < 0 || ky > 6) continue;
        #pragma unroll
        for (int kx = 0; kx < 7; ++kx){
          float wv = wr[ky*7 + kx];
          #pragma unroll
          for (int dx = 0; dx < 4; ++dx)
            acc[dy][dx] += wv * row[dx + kx];
        }
      }
    }
  }
  float g0 = gg[0], b0 = bb[0];
  #pragma unroll
  for (int dy = 0; dy < 4; ++dy){
    float4 o4;
    o4.x = sigm(acc[dy][0]*g0 + b0);
    o4.y = sigm(acc[dy][1]*g0 + b0);
    o4.z = sigm(acc[dy][2]*g0 + b0);
    o4.w = sigm(acc[dy][3]*g0 + b0);
    *(float4*)&G[(size_t)bw*4096 + (y0+dy)*64 + x0] = o4;
  }
}

// ============ K7: gated softmax + attn@v -> o (vectorized PV) ============
__global__ __launch_bounds__(256) void k_attn(const bf16* __restrict__ dots, const float* __restrict__ G1,
      const float* __restrict__ G2, const float* __restrict__ G3, const bf16* __restrict__ v,
      float* __restrict__ o){
  const int bw = blockIdx.x, hd = blockIdx.y;
  const int b = bw >> 8, wy = (bw >> 4) & 15, wx = bw & 15;
  __shared__ __align__(16) float attn[64][68];
  __shared__ __align__(16) short vst2[16][64];   // octet o of row d at [(o^(d>>2))*8]
  __shared__ float invTot[64];
  const int t = threadIdx.x;
  const short* vp = (const short*)v;
  for (int i = t; i < 1024; i += 256){
    int m = i >> 4, d = i & 15;
    int oo = m >> 3, rr = m & 7;
    vst2[d][((oo ^ (d >> 2)) << 3) + rr] = vp[(size_t)(bw*8+hd)*1024 + i];
  }
  const int n = t >> 2, j = t & 3;
  float g2v = G2[(size_t)bw*512 + n*8 + hd];
  const short* dp = (const short*)dots + ((size_t)(bw*8+hd)*64 + n)*64 + j*16;
  const float* g1p = G1 + (size_t)bw*512 + hd*64 + j*16;
  const float* g3p = G3 + (size_t)bw*4096 + n*64 + j*16;
  short8 d0 = *(const short8*)&dp[0];
  short8 d1 = *(const short8*)&dp[8];
  float e[16]; float mx = -1e30f;
  #pragma unroll
  for (int m = 0; m < 16; ++m){
    float dv = s2f(m < 8 ? d0[m] : d1[m-8]) * ((g1p[m] + g2v + g3p[m]) * (1.f/3.f));
    e[m] = dv; mx = fmaxf(mx, dv);
  }
  mx = fmaxf(mx, __shfl_xor(mx, 1, 4));
  mx = fmaxf(mx, __shfl_xor(mx, 2, 4));
  float s = 0.f;
  #pragma unroll
  for (int m = 0; m < 16; ++m){ float ev = expf(e[m]-mx); e[m] = ev; s += ev; }
  s += __shfl_xor(s, 1, 4);
  s += __shfl_xor(s, 2, 4);
  #pragma unroll
  for (int m = 0; m < 16; ++m) attn[n][j*16+m] = e[m];
  if (j == 0) invTot[n] = 1.f/s;
  __syncthreads();
  float acc4[4] = {0.f,0.f,0.f,0.f};
  #pragma unroll
  for (int oo = 0; oo < 8; ++oo){
    float4 a0 = *(const float4*)&attn[n][oo*8];
    float4 a1 = *(const float4*)&attn[n][oo*8+4];
    #pragma unroll
    for (int dd = 0; dd < 4; ++dd){
      short8 v8 = *(const short8*)&vst2[j*4+dd][((oo ^ j) << 3)];
      acc4[dd] += a0.x*s2f(v8[0]) + a0.y*s2f(v8[1]) + a0.z*s2f(v8[2]) + a0.w*s2f(v8[3])
                + a1.x*s2f(v8[4]) + a1.y*s2f(v8[5]) + a1.z*s2f(v8[6]) + a1.w*s2f(v8[7]);
    }
  }
  float it = invTot[n];
  int y = wy*8 + (n>>3), x = wx*8 + (n&7);
  #pragma unroll
  for (int dd = 0; dd < 4; ++dd){
    int c = hd*16 + j*4 + dd;
    o[((size_t)(b*128+c)*128 + y)*128 + x] = acc4[dd]*it;
  }
}

// ============ K8: Fh / Fw axial gates ============
__global__ void k_fw(const float* __restrict__ o, float* __restrict__ Fw){
  int t = blockIdx.x*256 + threadIdx.x; if (t >= 4*128*32*128) return;
  int x = t & 127, kk = (t>>7) & 31, bc = t >> 12;
  const float* p = o + ((size_t)bc*128 + kk*4)*128 + x;
  float mx = -1e30f, sm = 0.f;
  #pragma unroll
  for (int r = 0; r < 4; ++r){ float v = p[r*128]; mx = fmaxf(mx,v); sm += v; }
  Fw[t] = sigm(sm*0.25f + mx);
}
__global__ void k_fh(const float* __restrict__ o, float* __restrict__ Fh){
  int t = blockIdx.x*256 + threadIdx.x; if (t >= 4*128*128*32) return;
  int kk = t & 31, y = (t>>5) & 127, bc = t >> 12;
  const float* p = o + ((size_t)bc*128 + y)*128 + kk*4;
  float mx = -1e30f, sm = 0.f;
  #pragma unroll
  for (int r = 0; r < 4; ++r){ float v = p[r]; mx = fmaxf(mx,v); sm += v; }
  Fh[t] = sigm(sm*0.25f + mx);
}

// ============ K9: comb = o * (Fh@Fw) + local ============
__global__ __launch_bounds__(256) void k_comb(const float* __restrict__ o, const float* __restrict__ Fh,
      const float* __restrict__ Fw, const float* __restrict__ local, float* __restrict__ comb){
  const int bc = blockIdx.x;
  __shared__ float fh[128][33];
  __shared__ float fw[32][129];
  const int t = threadIdx.x;
  for (int i = t; i < 4096; i += 256) fh[i>>5][i&31]  = Fh[(size_t)bc*4096 + i];
  for (int i = t; i < 4096; i += 256) fw[i>>7][i&127] = Fw[(size_t)bc*4096 + i];
  __syncthreads();
  for (int i = t; i < 16384; i += 256){
    int y = i >> 7, x = i & 127;
    float g = 0.f;
    #pragma unroll
    for (int kk = 0; kk < 32; ++kk) g += fh[y][kk]*fw[kk][x];
    size_t idx = (size_t)bc*16384 + i;
    comb[idx] = o[idx]*g + local[idx];
  }
}

// ============ K10: reflect-pad + depthwise 8x8 + bn (register-tiled) ============
__global__ __launch_bounds__(256) void k_dw(const float* __restrict__ comb, const float* __restrict__ dw,
      const float* __restrict__ gg, const float* __restrict__ bb, float* __restrict__ out){
  const int bz = blockIdx.y;
  const int oy0 = blockIdx.x*16;
  const int c = bz & 127;
  __shared__ float xs[23][136];
  __shared__ float wsm[64];
  const int t = threadIdx.x;
  if (t < 64) wsm[t] = dw[c*64 + t];
  for (int i = t; i < 23*135; i += 256){
    int py = i / 135, px = i - py*135;
    int gy = oy0 + py - 3, gx = px - 3;
    float v = 0.f;
    if (gy >= 0 && gy <= 128 && gx >= 0 && gx <= 128){
      int yy = (gy==128)?126:gy, xx = (gx==128)?126:gx;
      v = comb[((size_t)bz*128 + yy)*128 + xx];
    }
    xs[py][px] = v;
  }
  __syncthreads();
  const int tx = t & 31, ty = t >> 5;
  const int x0 = tx*4, y0 = ty*2;
  float acc[2][4] = {};
  #pragma unroll
  for (int iy = 0; iy < 9; ++iy){
    float row[12];
    *(float4*)&row[0] = *(const float4*)&xs[y0+iy][x0];
    *(float4*)&row[4] = *(const float4*)&xs[y0+iy][x0+4];
    *(float4*)&row[8] = *(const float4*)&xs[y0+iy][x0+8];
    #pragma unroll
    for (int dy = 0; dy < 2; ++dy){
      const int ky = iy - dy;
      if (ky < 0 || ky > 7) continue;
      #pragma unroll
      for (int kx = 0; kx < 8; ++kx){
        float wv = wsm[ky*8 + kx];
        #pragma unroll
        for (int dx = 0; dx < 4; ++dx)
          acc[dy][dx] += wv * row[dx + kx];
      }
    }
  }
  float g = gg[c], bi = bb[c];
  #pragma unroll
  for (int dy = 0; dy < 2; ++dy){
    float4 o4;
    o4.x = acc[dy][0]*g + bi;
    o4.y = acc[dy][1]*g + bi;
    o4.z = acc[dy][2]*g + bi;
    o4.w = acc[dy][3]*g + bi;
    *(float4*)&out[((size_t)bz*128 + oy0 + y0 + dy)*128 + x0] = o4;
  }
}

// ============ P7: zero omT halo cols ============
__global__ void k_omzero(short* __restrict__ omT){
  int t = blockIdx.x*256 + threadIdx.x;
  int ci = t & 127, side = (t >> 7) & 1, row = t >> 8;
  int cpad = side ? 129 : 0;
  omT[((size_t)row*130 + cpad)*128 + ci] = 0;
}

// ============ P8: repack up_w -> wup[tap][co][ci] bf16 ============
__global__ __launch_bounds__(256) void k_uwrep(const float* __restrict__ w, short* __restrict__ wup){
  int i = blockIdx.x*256 + threadIdx.x;
  int ci = i & 127, co = (i >> 7) & 63, tap = i >> 13;
  wup[i] = f2bs(w[(co*128 + ci)*9 + tap]);
}

// ============ P10: proj_pw fp32 -> bf16 [co][ci] ============
__global__ __launch_bounds__(256) void k_wpwrep(const float* __restrict__ w, short* __restrict__ wpw){
  int i = blockIdx.x*256 + threadIdx.x;
  wpw[i] = f2bs(w[i]);
}

// ============ P11: proj1 NCHW fp32 -> p1T [b][pix][ci] bf16 ============
__global__ __launch_bounds__(256) void k_prep(const float* __restrict__ p1, short* __restrict__ p1T){
  const int blk = blockIdx.x;
  const int cgrp = blk & 1, cig = (blk >> 1) & 3, r = (blk >> 3) & 127, b = blk >> 10;
  const int c0 = cgrp*64, ci0 = cig*32;
  __shared__ float lds[32][65];
  const int t = threadIdx.x;
  for (int i = t; i < 2048; i += 256){
    int lci = i >> 6, c = i & 63;
    lds[lci][c] = p1[((size_t)(b*128 + ci0 + lci)*128 + r)*128 + c0 + c];
  }
  __syncthreads();
  for (int i = t; i < 2048; i += 256){
    int lci = i & 31, cc = i >> 5;
    p1T[((size_t)(b*128 + r)*128 + c0 + cc)*128 + ci0 + lci] = f2bs(lds[lci][cc]);
  }
}

// ============ K11: 1x1 proj conv 128->128 MFMA -> omT bf16 NHWC+halo ============
__global__ __launch_bounds__(256) void k_pwm(const short* __restrict__ p1T, const short* __restrict__ wpw,
      short* __restrict__ omT){
  int blk = blockIdx.x;
  blk = (blk & 7)*64 + (blk >> 3);           // XCD swizzle (grid 512)
  const int b = blk >> 7, y = blk & 127;
  const int t = threadIdx.x, lane = t & 63, wave = t >> 6;
  const int quad = lane >> 4, l15 = lane & 15;
  const int m0 = (wave >> 1)*64, n0 = (wave & 1)*64;
  __shared__ __align__(16) short smem[17408];   // as 4096 + bs 4096; epilogue tb[128][136]
  short* as = smem;
  short* bs = smem + 4096;
  const short* xrow = p1T + (size_t)(b*128 + y)*128*128;
  f32x4 acc[4][4];
  #pragma unroll
  for (int i = 0; i < 4; ++i)
    #pragma unroll
    for (int j = 0; j < 4; ++j) acc[i][j] = (f32x4){0.f,0.f,0.f,0.f};
  for (int ch = 0; ch < 4; ++ch){
    const int ci0 = ch*32;
    __syncthreads();
    for (int i = t; i < 512; i += 256){
      int col = i >> 2, cq = i & 3;
      *(uint4*)&as[(col*4 + SLOT(col,cq))*8] = *(const uint4*)&xrow[col*128 + ci0 + cq*8];
    }
    for (int i = t; i < 512; i += 256){
      int rr = i >> 2, cq = i & 3;
      *(uint4*)&bs[(rr*4 + SLOT(rr,cq))*8] = *(const uint4*)&wpw[rr*128 + ci0 + cq*8];
    }
    __syncthreads();
    short8 af[4], bf[4];
    #pragma unroll
    for (int mt = 0; mt < 4; ++mt){
      int row = m0 + mt*16 + l15;
      af[mt] = *(const short8*)&as[(row*4 + SLOT(row,quad))*8];
    }
    #pragma unroll
    for (int nt = 0; nt < 4; ++nt){
      int row = n0 + nt*16 + l15;
      bf[nt] = *(const short8*)&bs[(row*4 + SLOT(row,quad))*8];
    }
    #pragma unroll
    for (int mt = 0; mt < 4; ++mt)
      #pragma unroll
      for (int nt = 0; nt < 4; ++nt)
        acc[mt][nt] = __builtin_amdgcn_mfma_f32_16x16x32_bf16(af[mt], bf[nt], acc[mt][nt], 0, 0, 0);
  }
  // epilogue: transpose to [x][co] in LDS, vectorized omT row writes
  __syncthreads();
  short* tb = smem;   // [128][136]
  #pragma unroll
  for (int nt = 0; nt < 4; ++nt){
    int co = n0 + nt*16 + l15;
    #pragma unroll
    for (int mt = 0; mt < 4; ++mt){
      int xb = m0 + mt*16 + quad*4;
      #pragma unroll
      for (int r = 0; r < 4; ++r)
        tb[(xb + r)*136 + co] = f2bs(acc[mt][nt][r]);
    }
  }
  __syncthreads();
  for (int i = t; i < 2048; i += 256){
    int x = i >> 4, c8 = i & 15;
    *(uint4*)&omT[((size_t)(b*128 + y)*130 + x + 1)*128 + c8*8] = *(const uint4*)&tb[x*136 + c8*8];
  }
}

// ============ K12: transposed 3x3 stride-2 conv 128->64 (MFMA, parity decomp) ============
__global__ __launch_bounds__(256) void k_upm(const short* __restrict__ omT, const short* __restrict__ wup,
      float* __restrict__ out){
  int blk = blockIdx.x;
  blk = (blk & 7)*64 + (blk >> 3);           // XCD swizzle (grid 512)
  const int b = blk >> 7, y = blk & 127;
  const int t = threadIdx.x, lane = t & 63, wave = t >> 6;
  const int quad = lane >> 4, l15 = lane & 15;
  const int m0w = wave*32;
  __shared__ __align__(16) char smem[53504];
  short* asp = (short*)smem;
  short* bsp = (short*)(smem + 16640);
  float* ptile = (float*)smem;
  const int PAR[9] = {3,2,3, 1,0,1, 3,2,3};
  const int ROW[9] = {0,0,0, 0,0,0, 1,1,1};
  const int SHF[9] = {0,0,1, 0,0,1, 0,0,1};
  f32x4 acc[4][2][4];
  #pragma unroll
  for (int p = 0; p < 4; ++p)
    #pragma unroll
    for (int mt = 0; mt < 2; ++mt)
      #pragma unroll
      for (int nt = 0; nt < 4; ++nt) acc[p][mt][nt] = (f32x4){0.f,0.f,0.f,0.f};
  for (int ch = 0; ch < 4; ++ch){
    const int ci0 = ch*32;
    __syncthreads();
    for (int i = t; i < 1040; i += 256){
      int rw = (i >= 520), j = i - rw*520;
      int col = j >> 2, cq = j & 3;
      int row = rw*130 + col;
      uint4 val = {0,0,0,0};
      if (y + rw < 128)
        val = *(const uint4*)&omT[((size_t)(b*128 + y + rw)*130 + col)*128 + ci0 + cq*8];
      *(uint4*)&asp[(row*4 + SLOT(row,cq))*8] = val;
    }
    for (int i = t; i < 2304; i += 256){
      int rr = i >> 2, cq = i & 3;
      *(uint4*)&bsp[(rr*4 + SLOT(rr,cq))*8] = *(const uint4*)&wup[rr*128 + ci0 + cq*8];
    }
    __syncthreads();
    #pragma unroll
    for (int k = 0; k < 9; ++k){
      const int pr = PAR[k], rw = ROW[k], sh = SHF[k];
      if (rw && y == 127) continue;
      short8 af[2], bf[4];
      #pragma unroll
      for (int mt = 0; mt < 2; ++mt){
        int row = rw*130 + m0w + mt*16 + l15 + 1 + sh;
        af[mt] = *(const short8*)&asp[(row*4 + SLOT(row,quad))*8];
      }
      #pragma unroll
      for (int nt = 0; nt < 4; ++nt){
        int row = k*64 + nt*16 + l15;
        bf[nt] = *(const short8*)&bsp[(row*4 + SLOT(row,quad))*8];
      }
      #pragma unroll
      for (int mt = 0; mt < 2; ++mt)
        #pragma unroll
        for (int nt = 0; nt < 4; ++nt)
          acc[pr][mt][nt] = __builtin_amdgcn_mfma_f32_16x16x32_bf16(af[mt], bf[nt], acc[pr][mt][nt], 0, 0, 0);
    }
  }
  #pragma unroll
  for (int p = 0; p < 4; ++p){
    __syncthreads();
    #pragma unroll
    for (int mt = 0; mt < 2; ++mt)
      #pragma unroll
      for (int nt = 0; nt < 4; ++nt){
        int co = nt*16 + l15;
        int xb = m0w + mt*16 + quad*4;
        #pragma unroll
        for (int r = 0; r < 4; ++r)
          ptile[co*132 + xb + r] = acc[p][mt][nt][r];
      }
    __syncthreads();
    int py = p >> 1, px = p & 1;
    int Y = 2*y + py;
    for (int i = t; i < 8192; i += 256){
      int co = i >> 7, xx = i & 127;
      out[((size_t)(b*64 + co)*256 + Y)*256 + 2*xx + px] = ptile[co*132 + xx];
    }
  }
}

extern "C" void kernel_launch(void* const* d_in, const int* in_sizes, int n_in,
                              void* d_out, int out_size, void* d_ws, size_t ws_size,
                              hipStream_t stream) {
  const float* x       = (const float*)d_in[0];
  const float* conv_w  = (const float*)d_in[1];
  const float* bn1_g   = (const float*)d_in[2];
  const float* bn1_b   = (const float*)d_in[3];
  const float* qkv_w   = (const float*)d_in[4];
  const float* loc1_w  = (const float*)d_in[5];
  const float* loc1_g  = (const float*)d_in[6];
  const float* loc1_b  = (const float*)d_in[7];
  const float* loc2_w  = (const float*)d_in[8];
  const float* loc2_g  = (const float*)d_in[9];
  const float* loc2_b  = (const float*)d_in[10];
  const float* rel_t   = (const float*)d_in[11];
  const float* cw_w    = (const float*)d_in[12];
  const float* cw_g    = (const float*)d_in[13];
  const float* cw_b    = (const float*)d_in[14];
  const float* hc_w    = (const float*)d_in[15];
  const float* hc_g    = (const float*)d_in[16];
  const float* hc_b    = (const float*)d_in[17];
  const float* hw_w    = (const float*)d_in[18];
  const float* hw_g    = (const float*)d_in[19];
  const float* hw_b    = (const float*)d_in[20];
  const float* proj_dw = (const float*)d_in[21];
  const float* proj_g  = (const float*)d_in[22];
  const float* proj_b  = (const float*)d_in[23];
  const float* proj_pw = (const float*)d_in[24];
  const float* up_w    = (const float*)d_in[25];

  char* ws = (char*)d_ws;
  float* local  = (float*)(ws + OFF_LOCAL);
  bf16*  q      = (bf16*)(ws + OFF_Q);
  bf16*  k      = (bf16*)(ws + OFF_K);
  bf16*  v      = (bf16*)(ws + OFF_V);
  bf16*  dots   = (bf16*)(ws + OFF_DOTS);
  bf16*  z1     = (bf16*)(ws + OFF_Z1);
  bf16*  z2     = (bf16*)(ws + OFF_Z2);
  bf16*  z3     = (bf16*)(ws + OFF_Z3);
  float* G1     = (float*)(ws + OFF_G1);
  float* G2     = (float*)(ws + OFF_G2);
  float* G3     = (float*)(ws + OFF_G3);
  short* xT     = (short*)(ws + OFF_DOTS);
  short* hT     = (short*)(ws + OFF_HT);
  short* w2bf   = (short*)(ws + OFF_Z1);
  short* wloc   = (short*)(ws + OFF_Z2);
  short* wqkv   = (short*)(ws + OFF_Z3);
  short* omT    = (short*)(ws + OFF_DOTS);
  short* wup    = (short*)(ws + OFF_Z1);
  short* wpw    = (short*)(ws + OFF_Z2);
  short* p1T    = (short*)(ws + OFF_K);
  float* o_img  = (float*)(ws + OFF_Q);
  float* Fh     = (float*)(ws + OFF_DOTS);
  float* Fw     = (float*)(ws + OFF_DOTS + 8388608);
  float* comb   = (float*)(ws + OFF_H);
  float* proj1  = (float*)(ws + OFF_LOCAL);
  float* outp   = (float*)d_out;

  k_wrep <<<1152, 256, 0, stream>>>(conv_w, w2bf);
  k_xzero<<<1024, 256, 0, stream>>>(xT);
  k_xrep <<<8192, 256, 0, stream>>>(x, xT);
  k_hzero<<<512, 256, 0, stream>>>(hT);
  k_conv1m<<<1024, 256, 0, stream>>>(xT, w2bf, bn1_g, bn1_b, hT);
  k_lwrep<<<576, 256, 0, stream>>>(loc1_w, loc1_g, loc2_w, loc2_g, wloc);
  k_localm<<<1024, 256, 0, stream>>>(hT, wloc, loc1_b, loc2_b, local);
  k_wqkvrep<<<192, 256, 0, stream>>>(qkv_w, wqkv);
  k_qkvm <<<dim3(512,3), 256, 0, stream>>>(hT, wqkv, q, k, v);
  k_dots <<<dim3(NWIN,8), 256, 0, stream>>>(q, k, rel_t, dots);
  k_zall <<<NWIN, 256, 0, stream>>>(dots, z1, z2, z3);
  k_gate <<<dim3(NWIN,2),  256, 0, stream>>>(z1, cw_w, cw_g, cw_b, G1, 8, 64);
  k_gate <<<dim3(NWIN,2),  256, 0, stream>>>(z2, hc_w, hc_g, hc_b, G2, 64, 8);
  k_gate3<<<NWIN, 256, 0, stream>>>(z3, hw_w, hw_g, hw_b, G3);
  k_attn <<<dim3(NWIN,8), 256, 0, stream>>>(dots, G1, G2, G3, v, o_img);
  k_fw   <<<8192, 256, 0, stream>>>(o_img, Fw);
  k_fh   <<<8192, 256, 0, stream>>>(o_img, Fh);
  k_comb <<<512, 256, 0, stream>>>(o_img, Fh, Fw, local, comb);
  k_dw   <<<dim3(8, BB*128), 256, 0, stream>>>(comb, proj_dw, proj_g, proj_b, proj1);
  k_omzero<<<512, 256, 0, stream>>>(omT);
  k_uwrep<<<288, 256, 0, stream>>>(up_w, wup);
  k_wpwrep<<<64, 256, 0, stream>>>(proj_pw, wpw);
  k_prep <<<4096, 256, 0, stream>>>(proj1, p1T);
  k_pwm  <<<512, 256, 0, stream>>>(p1T, wpw, omT);
  k_upm  <<<512, 256, 0, stream>>>(omT, wup, outp);
}

// Round 11
// 601.053 us; speedup vs baseline: 1.1536x; 1.0193x over previous
//
#include <hip/hip_runtime.h>
#include <hip/hip_bf16.h>

typedef __hip_bfloat16 bf16;
typedef __attribute__((ext_vector_type(8))) short short8;
typedef __attribute__((ext_vector_type(4))) float f32x4;

#define DEV __device__ __forceinline__
DEV float b2f(bf16 v){ return __bfloat162float(v); }
DEV bf16 f2b(float v){ return __float2bfloat16(v); }
DEV short f2bs(float v){ union{ bf16 b; short s; } u; u.b = __float2bfloat16(v); return u.s; }
DEV float s2f(short s){ union{ short s; bf16 b; } u; u.s = s; return __bfloat162float(u.b); }
DEV float sigm(float x){ return 1.f/(1.f + expf(-x)); }

// ---- problem constants ----
#define BB 4
#define CIN 256
#define MID 128
#define COUT 64
#define HH 128
#define WW 128
#define WS 8
#define HEADS 8
#define HD 16
#define NTOK 64
#define NWIN 1024

// LDS slot swizzle: row-major 64B rows, slot = cq ^ ((row>>1)&3)
#define SLOT(row,cq) ((cq) ^ (((row)>>1)&3))

// ---- workspace layout (bytes) ----
static const size_t OFF_H     = 0;
static const size_t OFF_LOCAL = 33554432;
static const size_t OFF_Q     = 67108864;
static const size_t OFF_K     = 83886080;
static const size_t OFF_V     = 100663296;
static const size_t OFF_DOTS  = 117440512;
static const size_t OFF_Z1    = 184549376;
static const size_t OFF_Z2    = 186646528;
static const size_t OFF_Z3    = 188743680;
static const size_t OFF_G1    = 205520896;
static const size_t OFF_G2    = 207618048;
static const size_t OFF_G3    = 209715200;
static const size_t OFF_HT    = OFF_DOTS + 34078720;

// ============ P1: repack conv_w -> w2[kk][co][ci] bf16 ============
__global__ __launch_bounds__(256) void k_wrep(const float* __restrict__ w, short* __restrict__ w2){
  int i = blockIdx.x*256 + threadIdx.x;
  int ci = i & 255, co = (i >> 8) & 127, kk = i >> 15;
  w2[i] = f2bs(w[(co*256 + ci)*9 + kk]);
}

// ============ P2: zero pad columns of xT ============
__global__ void k_xzero(short* __restrict__ xT){
  int t = blockIdx.x*256 + threadIdx.x;
  int ci = t & 255, side = (t >> 8) & 1, row = t >> 9;
  int cpad = side ? 129 : 0;
  xT[((size_t)row*130 + cpad)*256 + ci] = 0;
}

// ============ P3: x NCHW fp32 -> xT[b][r][c+1][ci] bf16 ============
__global__ __launch_bounds__(256) void k_xrep(const float* __restrict__ x, short* __restrict__ xT){
  const int blk = blockIdx.x;
  const int cgrp = blk & 1, cig = (blk >> 1) & 7, r = (blk >> 4) & 127, b = blk >> 11;
  const int c0 = cgrp*64, ci0 = cig*32;
  __shared__ float lds[32][65];
  const int t = threadIdx.x;
  for (int i = t; i < 2048; i += 256){
    int lci = i >> 6, c = i & 63;
    lds[lci][c] = x[((size_t)(b*256 + ci0 + lci)*128 + r)*128 + c0 + c];
  }
  __syncthreads();
  for (int i = t; i < 2048; i += 256){
    int lci = i & 31, cc = i >> 5;
    xT[((size_t)(b*128 + r)*130 + c0 + cc + 1)*256 + ci0 + lci] = f2bs(lds[lci][cc]);
  }
}

// ============ K1: conv3x3 256->128 + bn + relu -> hT bf16 ============
// 1-row co-split blocks (grid 1024, high occupancy) + SLOT-swizzled LDS (conflict-free).
__global__ __launch_bounds__(256) void k_conv1m(const short* __restrict__ xT, const short* __restrict__ w2,
      const float* __restrict__ gg, const float* __restrict__ bb, short* __restrict__ hT){
  int blk = blockIdx.x;
  blk = (blk & 7)*128 + (blk >> 3);          // XCD swizzle (grid 1024)
  const int cg = blk & 1, y = (blk >> 1) & 127, b = blk >> 8;
  const int t = threadIdx.x, lane = t & 63, wave = t >> 6;
  const int quad = lane >> 4, l15 = lane & 15;
  const int m0 = wave*32;
  __shared__ __align__(16) short smem[10304];   // as 130*32 + bs 192*32
  short* as = smem;           // (col*4 + SLOT(col,cq))*8
  short* bs = smem + 4160;    // (rr*4 + SLOT(rr,cq))*8, rr = kx*64+co_l
  f32x4 acc[2][4];
  #pragma unroll
  for (int i = 0; i < 2; ++i)
    #pragma unroll
    for (int j = 0; j < 4; ++j) acc[i][j] = (f32x4){0.f,0.f,0.f,0.f};
  for (int ky = 0; ky < 3; ++ky){
    int r = y + ky - 1;
    if ((unsigned)r >= 128u) continue;
    const short* xrow = xT + (size_t)(b*128 + r)*130*256;
    const short* wk   = w2 + (size_t)(ky*384 + cg*64)*256;
    for (int ch = 0; ch < 8; ++ch){
      const int ci0 = ch*32;
      __syncthreads();
      for (int i = t; i < 520; i += 256){
        int col = i >> 2, cq = i & 3;
        *(uint4*)&as[(col*4 + SLOT(col,cq))*8] = *(const uint4*)&xrow[col*256 + ci0 + cq*8];
      }
      for (int i = t; i < 768; i += 256){
        int rr = i >> 2, cq = i & 3;
        *(uint4*)&bs[(rr*4 + SLOT(rr,cq))*8] =
          *(const uint4*)&wk[(((rr >> 6)<<7) + (rr & 63))*256 + ci0 + cq*8];
      }
      __syncthreads();
      #pragma unroll
      for (int kx = 0; kx < 3; ++kx){
        short8 af[2], bf[4];
        #pragma unroll
        for (int mt = 0; mt < 2; ++mt){
          int col = m0 + mt*16 + l15 + kx;
          af[mt] = *(const short8*)&as[(col*4 + SLOT(col,quad))*8];
        }
        #pragma unroll
        for (int nt = 0; nt < 4; ++nt){
          int rr = kx*64 + nt*16 + l15;
          bf[nt] = *(const short8*)&bs[(rr*4 + SLOT(rr,quad))*8];
        }
        #pragma unroll
        for (int mt = 0; mt < 2; ++mt)
          #pragma unroll
          for (int nt = 0; nt < 4; ++nt)
            acc[mt][nt] = __builtin_amdgcn_mfma_f32_16x16x32_bf16(af[mt], bf[nt], acc[mt][nt], 0, 0, 0);
      }
    }
  }
  // epilogue: bn+relu, transpose via LDS, write bf16 NHWC rows of hT
  __syncthreads();
  short* tb = smem;   // [128][72] bf16 (x, co_local)
  #pragma unroll
  for (int nt = 0; nt < 4; ++nt){
    int cl = nt*16 + l15, co = cg*64 + cl;
    float g = gg[co], bia = bb[co];
    #pragma unroll
    for (int mt = 0; mt < 2; ++mt){
      int xb = m0 + mt*16 + quad*4;
      #pragma unroll
      for (int r2 = 0; r2 < 4; ++r2)
        tb[(xb + r2)*72 + cl] = f2bs(fmaxf(acc[mt][nt][r2]*g + bia, 0.f));
    }
  }
  __syncthreads();
  for (int i = t; i < 1024; i += 256){
    int xx = i >> 3, c8 = i & 7;
    *(uint4*)&hT[((size_t)(b*128 + y)*130 + xx + 1)*128 + cg*64 + c8*8] = *(const uint4*)&tb[xx*72 + c8*8];
  }
}

// ============ P4: zero pad columns of hT ============
__global__ void k_hzero(short* __restrict__ hT){
  int t = blockIdx.x*256 + threadIdx.x;
  int ci = t & 127, side = (t >> 7) & 1, row = t >> 8;
  int cpad = side ? 129 : 0;
  hT[((size_t)row*130 + cpad)*128 + ci] = 0;
}

// ============ P6: fold local weights: wloc[kk][co][ci] bf16 ============
__global__ __launch_bounds__(256) void k_lwrep(const float* __restrict__ w1, const float* __restrict__ g1,
      const float* __restrict__ w2, const float* __restrict__ g2, short* __restrict__ wloc){
  int i = blockIdx.x*256 + threadIdx.x;
  int ci = i & 127, row = (i >> 7) % 384, ky = i / 49152;
  int kx = row >> 7, co = row & 127;
  float v = w1[(co*128 + ci)*9 + ky*3 + kx] * g1[co];
  if (ky == 1 && kx == 1) v += w2[co*128 + ci] * g2[co];
  wloc[i] = f2bs(v);
}

// ============ K2: local conv (folded 3x3+1x1), 1-row blocks, SLOT LDS ============
__global__ __launch_bounds__(256) void k_localm(const short* __restrict__ hT, const short* __restrict__ wloc,
      const float* __restrict__ b1, const float* __restrict__ b2, float* __restrict__ out){
  int blk = blockIdx.x;
  blk = (blk & 7)*128 + (blk >> 3);          // XCD swizzle (grid 1024)
  const int cg = blk & 1, y = (blk >> 1) & 127, b = blk >> 8;
  const int t = threadIdx.x, lane = t & 63, wave = t >> 6;
  const int quad = lane >> 4, l15 = lane & 15;
  const int m0 = wave*32;
  __shared__ __align__(16) short smem2[10304];
  short* as = smem2;
  short* bs = smem2 + 4160;
  f32x4 acc[2][4];
  #pragma unroll
  for (int i = 0; i < 2; ++i)
    #pragma unroll
    for (int j = 0; j < 4; ++j) acc[i][j] = (f32x4){0.f,0.f,0.f,0.f};
  for (int ky = 0; ky < 3; ++ky){
    int r = y + ky - 1;
    if ((unsigned)r >= 128u) continue;
    const short* xrow = hT + (size_t)(b*128 + r)*130*128;
    const short* wk   = wloc + (size_t)(ky*384 + cg*64)*128;
    for (int ch = 0; ch < 4; ++ch){
      const int ci0 = ch*32;
      __syncthreads();
      for (int i = t; i < 520; i += 256){
        int col = i >> 2, cq = i & 3;
        *(uint4*)&as[(col*4 + SLOT(col,cq))*8] = *(const uint4*)&xrow[col*128 + ci0 + cq*8];
      }
      for (int i = t; i < 768; i += 256){
        int rr = i >> 2, cq = i & 3;
        *(uint4*)&bs[(rr*4 + SLOT(rr,cq))*8] =
          *(const uint4*)&wk[(((rr >> 6)<<7) + (rr & 63))*128 + ci0 + cq*8];
      }
      __syncthreads();
      #pragma unroll
      for (int kx = 0; kx < 3; ++kx){
        short8 af[2], bf[4];
        #pragma unroll
        for (int mt = 0; mt < 2; ++mt){
          int col = m0 + mt*16 + l15 + kx;
          af[mt] = *(const short8*)&as[(col*4 + SLOT(col,quad))*8];
        }
        #pragma unroll
        for (int nt = 0; nt < 4; ++nt){
          int rr = kx*64 + nt*16 + l15;
          bf[nt] = *(const short8*)&bs[(rr*4 + SLOT(rr,quad))*8];
        }
        #pragma unroll
        for (int mt = 0; mt < 2; ++mt)
          #pragma unroll
          for (int nt = 0; nt < 4; ++nt)
            acc[mt][nt] = __builtin_amdgcn_mfma_f32_16x16x32_bf16(af[mt], bf[nt], acc[mt][nt], 0, 0, 0);
      }
    }
  }
  #pragma unroll
  for (int nt = 0; nt < 4; ++nt){
    int co = cg*64 + nt*16 + l15;
    float bia = b1[co] + b2[co];
    #pragma unroll
    for (int mt = 0; mt < 2; ++mt){
      int xb = m0 + mt*16 + quad*4;
      float4 o4;
      o4.x = acc[mt][nt][0] + bia;
      o4.y = acc[mt][nt][1] + bia;
      o4.z = acc[mt][nt][2] + bia;
      o4.w = acc[mt][nt][3] + bia;
      *(float4*)&out[((size_t)(b*128 + co)*128 + y)*128 + xb] = o4;
    }
  }
}

// ============ P9: qkv_w fp32 -> bf16 [oc][ci] ============
__global__ __launch_bounds__(256) void k_wqkvrep(const float* __restrict__ w, short* __restrict__ wqkv){
  int i = blockIdx.x*256 + threadIdx.x;
  wqkv[i] = f2bs(w[i]);
}

// ============ K3: qkv 1x1 conv (MFMA GEMM over hT) -> windowed q,k,v ============
__global__ __launch_bounds__(256) void k_qkvm(const short* __restrict__ hT, const short* __restrict__ wqkv,
      bf16* __restrict__ q, bf16* __restrict__ k, bf16* __restrict__ v){
  const int blk = blockIdx.x, ocg = blockIdx.y;
  const int b = blk >> 7, y = blk & 127;
  const int t = threadIdx.x, lane = t & 63, wave = t >> 6;
  const int quad = lane >> 4, l15 = lane & 15;
  const int m0 = (wave >> 1)*64, n0 = (wave & 1)*64;
  __shared__ __align__(16) short asq[4096];   // (col*4 + SLOT(col,cq))*8
  __shared__ __align__(16) short bsq[4096];
  const short* xrow = hT + ((size_t)(b*128 + y)*130 + 1)*128;
  const short* wk   = wqkv + (size_t)ocg*128*128;
  f32x4 acc[4][4];
  #pragma unroll
  for (int i = 0; i < 4; ++i)
    #pragma unroll
    for (int j = 0; j < 4; ++j) acc[i][j] = (f32x4){0.f,0.f,0.f,0.f};
  for (int ch = 0; ch < 4; ++ch){
    const int ci0 = ch*32;
    __syncthreads();
    for (int i = t; i < 512; i += 256){
      int col = i >> 2, cq = i & 3;
      *(uint4*)&asq[(col*4 + SLOT(col,cq))*8] = *(const uint4*)&xrow[col*128 + ci0 + cq*8];
    }
    for (int i = t; i < 512; i += 256){
      int rr = i >> 2, cq = i & 3;
      *(uint4*)&bsq[(rr*4 + SLOT(rr,cq))*8] = *(const uint4*)&wk[rr*128 + ci0 + cq*8];
    }
    __syncthreads();
    short8 af[4], bf[4];
    #pragma unroll
    for (int mt = 0; mt < 4; ++mt){
      int row = m0 + mt*16 + l15;
      af[mt] = *(const short8*)&asq[(row*4 + SLOT(row,quad))*8];
    }
    #pragma unroll
    for (int nt = 0; nt < 4; ++nt){
      int row = n0 + nt*16 + l15;
      bf[nt] = *(const short8*)&bsq[(row*4 + SLOT(row,quad))*8];
    }
    #pragma unroll
    for (int mt = 0; mt < 4; ++mt)
      #pragma unroll
      for (int nt = 0; nt < 4; ++nt)
        acc[mt][nt] = __builtin_amdgcn_mfma_f32_16x16x32_bf16(af[mt], bf[nt], acc[mt][nt], 0, 0, 0);
  }
  bf16* dst = (ocg == 0) ? q : (ocg == 1) ? k : v;
  const int iy = y & 7, hy = y >> 3;
  #pragma unroll
  for (int nt = 0; nt < 4; ++nt){
    int co = n0 + nt*16 + l15;
    int head = co >> 4, d = co & 15;
    #pragma unroll
    for (int mt = 0; mt < 4; ++mt){
      int xb = m0 + mt*16 + quad*4;
      #pragma unroll
      for (int rr = 0; rr < 4; ++rr){
        int x = xb + rr;
        int bw = b*256 + hy*16 + (x >> 3);
        int n = iy*8 + (x & 7);
        dst[((size_t)(bw*8+head)*64 + n)*16 + d] = f2b(acc[mt][nt][rr]);
      }
    }
  }
}

// ============ K4: dots = q.k^T * 0.25 + relpos bias (vectorized) ============
__global__ __launch_bounds__(256) void k_dots(const bf16* __restrict__ q, const bf16* __restrict__ kk,
      const float* __restrict__ rel, bf16* __restrict__ dots){
  const int bw = blockIdx.x, hd = blockIdx.y;
  __shared__ __align__(16) short qs[64][16];
  __shared__ __align__(16) short ks2[64][16];   // octet s of row m at [(s^((m>>4)&1))*8]
  const int t = threadIdx.x;
  const size_t base = (size_t)(bw*8+hd)*1024;
  const short* qp = (const short*)q;
  const short* kp = (const short*)kk;
  if (t < 64){
    *(uint4*)&qs[t][0] = *(const uint4*)&qp[base + t*16];
    *(uint4*)&qs[t][8] = *(const uint4*)&qp[base + t*16 + 8];
  } else if (t < 128){
    int r = t - 64;
    uint4 a0 = *(const uint4*)&kp[base + r*16];
    uint4 a1 = *(const uint4*)&kp[base + r*16 + 8];
    int p = (r >> 4) & 1;
    *(uint4*)&ks2[r][p*8]     = a0;
    *(uint4*)&ks2[r][8 - p*8] = a1;
  }
  __syncthreads();
  const int n = t >> 2, jm = t & 3;
  float qr[16];
  short8 q0 = *(const short8*)&qs[n][0];
  short8 q1 = *(const short8*)&qs[n][8];
  #pragma unroll
  for (int d = 0; d < 8; ++d){ qr[d] = s2f(q0[d]); qr[8+d] = s2f(q1[d]); }
  const int ny = n >> 3, nx = n & 7;
  float a[16];
  #pragma unroll
  for (int mm = 0; mm < 16; ++mm){
    int m = jm*16 + mm;
    int p = (m >> 4) & 1;
    short8 k0 = *(const short8*)&ks2[m][p*8];
    short8 k1 = *(const short8*)&ks2[m][8 - p*8];
    float acc = 0.f;
    #pragma unroll
    for (int d = 0; d < 8; ++d) acc += qr[d]*s2f(k0[d]);
    #pragma unroll
    for (int d = 0; d < 8; ++d) acc += qr[8+d]*s2f(k1[d]);
    int my = m >> 3, mx = m & 7;
    int ridx = (ny - my + 7)*15 + (nx - mx + 7);
    a[mm] = acc*0.25f + rel[ridx*8 + hd];
  }
  short8 s0, s1;
  #pragma unroll
  for (int j = 0; j < 8; ++j){ s0[j] = f2bs(a[j]); s1[j] = f2bs(a[8+j]); }
  short* dp = (short*)dots + base*4 + (size_t)n*64 + jm*16;
  *(short8*)&dp[0] = s0;
  *(short8*)&dp[8] = s1;
}

// ============ K5: fused axis reductions (z1 + z2 + z3 in one pass) ============
__global__ __launch_bounds__(256) void k_zall(const bf16* __restrict__ dots,
      bf16* __restrict__ z1, bf16* __restrict__ z2, bf16* __restrict__ z3){
  const int bw = blockIdx.x;
  const int t = threadIdx.x;
  const int q4 = t >> 2, j4 = t & 3;
  __shared__ float sd[64][65];
  float mx3[16], sm3[16];
  #pragma unroll
  for (int i = 0; i < 16; ++i){ mx3[i] = -1e30f; sm3[i] = 0.f; }
  const short* dp = (const short*)dots + (size_t)bw*32768;
  for (int hd = 0; hd < 8; ++hd){
    __syncthreads();
    const short* p = dp + (size_t)hd*4096;
    #pragma unroll
    for (int g = 0; g < 2; ++g){
      short8 s8 = *(const short8*)&p[t*16 + g*8];
      #pragma unroll
      for (int j = 0; j < 8; ++j){
        float vv = s2f(s8[j]);
        sd[q4][j4*16 + g*8 + j] = vv;
        mx3[g*8+j] = fmaxf(mx3[g*8+j], vv);
        sm3[g*8+j] += vv;
      }
    }
    __syncthreads();
    float mx = -1e30f, sm = 0.f;
    #pragma unroll
    for (int m = 0; m < 16; ++m){
      float vv = sd[q4][j4*16 + m];
      mx = fmaxf(mx, vv); sm += vv;
    }
    mx = fmaxf(mx, __shfl_xor(mx, 1, 4));
    mx = fmaxf(mx, __shfl_xor(mx, 2, 4));
    sm += __shfl_xor(sm, 1, 4);
    sm += __shfl_xor(sm, 2, 4);
    if (j4 == 0){
      z2[(size_t)bw*1024 + q4*8 + hd]       = f2b(mx);
      z2[(size_t)bw*1024 + 512 + q4*8 + hd] = f2b(sm*(1.f/64.f));
    }
    float mxc = -1e30f, smc = 0.f;
    #pragma unroll
    for (int nn = 0; nn < 16; ++nn){
      float vv = sd[j4*16 + nn][q4];
      mxc = fmaxf(mxc, vv); smc += vv;
    }
    mxc = fmaxf(mxc, __shfl_xor(mxc, 1, 4));
    mxc = fmaxf(mxc, __shfl_xor(mxc, 2, 4));
    smc += __shfl_xor(smc, 1, 4);
    smc += __shfl_xor(smc, 2, 4);
    if (j4 == 0){
      z1[(size_t)bw*1024 + hd*64 + q4]       = f2b(mxc);
      z1[(size_t)bw*1024 + 512 + hd*64 + q4] = f2b(smc*(1.f/64.f));
    }
  }
  short* zp = (short*)z3 + (size_t)bw*8192;
  short8 o0, o1, p0, p1;
  #pragma unroll
  for (int j = 0; j < 8; ++j){
    o0[j] = f2bs(mx3[j]);        o1[j] = f2bs(mx3[8+j]);
    p0[j] = f2bs(sm3[j]*0.125f); p1[j] = f2bs(sm3[8+j]*0.125f);
  }
  *(short8*)&zp[t*16]          = o0;
  *(short8*)&zp[t*16 + 8]      = o1;
  *(short8*)&zp[4096 + t*16]   = p0;
  *(short8*)&zp[4096 + t*16+8] = p1;
}

// ============ K6: generic 7x7 2->1 conv + bn + sigmoid (small gates) ============
__global__ __launch_bounds__(256) void k_gate(const bf16* __restrict__ z, const float* __restrict__ w,
      const float* __restrict__ gg, const float* __restrict__ bb, float* __restrict__ G, int R, int C){
  __shared__ float wsm[98];
  const int t = threadIdx.x;
  if (t < 98) wsm[t] = w[t];
  __syncthreads();
  const int bw = blockIdx.x;
  int p = blockIdx.y*256 + t; if (p >= R*C) return;
  int y = p / C, x = p - y*C;
  float acc = 0.f;
  for (int c = 0; c < 2; ++c)
    for (int ky = 0; ky < 7; ++ky){
      int iy = y + ky - 3; if ((unsigned)iy >= (unsigned)R) continue;
      for (int kx = 0; kx < 7; ++kx){
        int ix = x + kx - 3; if ((unsigned)ix >= (unsigned)C) continue;
        acc += b2f(z[((size_t)(bw*2+c)*R + iy)*C + ix]) * wsm[c*49 + ky*7 + kx];
      }
    }
  G[(size_t)bw*R*C + p] = sigm(acc*gg[0] + bb[0]);
}

// ============ K6b: specialized 64x64 gate (G3) ============
__global__ __launch_bounds__(256) void k_gate3(const bf16* __restrict__ z, const float* __restrict__ w,
      const float* __restrict__ gg, const float* __restrict__ bb, float* __restrict__ G){
  const int bw = blockIdx.x;
  __shared__ float pad[2][70][72];
  __shared__ float wsm[98];
  const int t = threadIdx.x;
  if (t < 98) wsm[t] = w[t];
  for (int i = t; i < 2*70*70; i += 256){
    int c = i / 4900, r = i % 4900;
    int py = r / 70, px = r % 70;
    int y = py - 3, x = px - 3;
    float v = 0.f;
    if ((unsigned)y < 64u && (unsigned)x < 64u)
      v = b2f(z[(size_t)bw*8192 + c*4096 + y*64 + x]);
    pad[c][py][px] = v;
  }
  __syncthreads();
  const int tx = t & 15, ty = t >> 4;
  const int x0 = tx*4, y0 = ty*4;
  float acc[4][4] = {};
  #pragma unroll
  for (int c = 0; c < 2; ++c){
    float wr[49];
    #pragma unroll
    for (int kk = 0; kk < 49; ++kk) wr[kk] = wsm[c*49 + kk];
    #pragma unroll
    for (int iy = 0; iy < 10; ++iy){
      float row[10];
      #pragma unroll
      for (int j = 0; j < 10; ++j) row[j] = pad[c][y0+iy][x0+j];
      #pragma unroll
      for (int dy = 0; dy < 4; ++dy){
        const int ky = iy - dy;
        if (ky < 0 || ky > 6) continue;
        #pragma unroll
        for (int kx = 0; kx < 7; ++kx){
          float wv = wr[ky*7 + kx];
          #pragma unroll
          for (int dx = 0; dx < 4; ++dx)
            acc[dy][dx] += wv * row[dx + kx];
        }
      }
    }
  }
  float g0 = gg[0], b0 = bb[0];
  #pragma unroll
  for (int dy = 0; dy < 4; ++dy){
    float4 o4;
    o4.x = sigm(acc[dy][0]*g0 + b0);
    o4.y = sigm(acc[dy][1]*g0 + b0);
    o4.z = sigm(acc[dy][2]*g0 + b0);
    o4.w = sigm(acc[dy][3]*g0 + b0);
    *(float4*)&G[(size_t)bw*4096 + (y0+dy)*64 + x0] = o4;
  }
}

// ============ K7: gated softmax + attn@v -> o (vectorized PV) ============
__global__ __launch_bounds__(256) void k_attn(const bf16* __restrict__ dots, const float* __restrict__ G1,
      const float* __restrict__ G2, const float* __restrict__ G3, const bf16* __restrict__ v,
      float* __restrict__ o){
  const int bw = blockIdx.x, hd = blockIdx.y;
  const int b = bw >> 8, wy = (bw >> 4) & 15, wx = bw & 15;
  __shared__ __align__(16) float attn[64][68];
  __shared__ __align__(16) short vst2[16][64];   // octet o of row d at [(o^(d>>2))*8]
  __shared__ float invTot[64];
  const int t = threadIdx.x;
  const short* vp = (const short*)v;
  for (int i = t; i < 1024; i += 256){
    int m = i >> 4, d = i & 15;
    int oo = m >> 3, rr = m & 7;
    vst2[d][((oo ^ (d >> 2)) << 3) + rr] = vp[(size_t)(bw*8+hd)*1024 + i];
  }
  const int n = t >> 2, j = t & 3;
  float g2v = G2[(size_t)bw*512 + n*8 + hd];
  const short* dp = (const short*)dots + ((size_t)(bw*8+hd)*64 + n)*64 + j*16;
  const float* g1p = G1 + (size_t)bw*512 + hd*64 + j*16;
  const float* g3p = G3 + (size_t)bw*4096 + n*64 + j*16;
  short8 d0 = *(const short8*)&dp[0];
  short8 d1 = *(const short8*)&dp[8];
  float e[16]; float mx = -1e30f;
  #pragma unroll
  for (int m = 0; m < 16; ++m){
    float dv = s2f(m < 8 ? d0[m] : d1[m-8]) * ((g1p[m] + g2v + g3p[m]) * (1.f/3.f));
    e[m] = dv; mx = fmaxf(mx, dv);
  }
  mx = fmaxf(mx, __shfl_xor(mx, 1, 4));
  mx = fmaxf(mx, __shfl_xor(mx, 2, 4));
  float s = 0.f;
  #pragma unroll
  for (int m = 0; m < 16; ++m){ float ev = expf(e[m]-mx); e[m] = ev; s += ev; }
  s += __shfl_xor(s, 1, 4);
  s += __shfl_xor(s, 2, 4);
  #pragma unroll
  for (int m = 0; m < 16; ++m) attn[n][j*16+m] = e[m];
  if (j == 0) invTot[n] = 1.f/s;
  __syncthreads();
  float acc4[4] = {0.f,0.f,0.f,0.f};
  #pragma unroll
  for (int oo = 0; oo < 8; ++oo){
    float4 a0 = *(const float4*)&attn[n][oo*8];
    float4 a1 = *(const float4*)&attn[n][oo*8+4];
    #pragma unroll
    for (int dd = 0; dd < 4; ++dd){
      short8 v8 = *(const short8*)&vst2[j*4+dd][((oo ^ j) << 3)];
      acc4[dd] += a0.x*s2f(v8[0]) + a0.y*s2f(v8[1]) + a0.z*s2f(v8[2]) + a0.w*s2f(v8[3])
                + a1.x*s2f(v8[4]) + a1.y*s2f(v8[5]) + a1.z*s2f(v8[6]) + a1.w*s2f(v8[7]);
    }
  }
  float it = invTot[n];
  int y = wy*8 + (n>>3), x = wx*8 + (n&7);
  #pragma unroll
  for (int dd = 0; dd < 4; ++dd){
    int c = hd*16 + j*4 + dd;
    o[((size_t)(b*128+c)*128 + y)*128 + x] = acc4[dd]*it;
  }
}

// ============ K8: Fh / Fw axial gates ============
__global__ void k_fw(const float* __restrict__ o, float* __restrict__ Fw){
  int t = blockIdx.x*256 + threadIdx.x; if (t >= 4*128*32*128) return;
  int x = t & 127, kk = (t>>7) & 31, bc = t >> 12;
  const float* p = o + ((size_t)bc*128 + kk*4)*128 + x;
  float mx = -1e30f, sm = 0.f;
  #pragma unroll
  for (int r = 0; r < 4; ++r){ float v = p[r*128]; mx = fmaxf(mx,v); sm += v; }
  Fw[t] = sigm(sm*0.25f + mx);
}
__global__ void k_fh(const float* __restrict__ o, float* __restrict__ Fh){
  int t = blockIdx.x*256 + threadIdx.x; if (t >= 4*128*128*32) return;
  int kk = t & 31, y = (t>>5) & 127, bc = t >> 12;
  const float* p = o + ((size_t)bc*128 + y)*128 + kk*4;
  float mx = -1e30f, sm = 0.f;
  #pragma unroll
  for (int r = 0; r < 4; ++r){ float v = p[r]; mx = fmaxf(mx,v); sm += v; }
  Fh[t] = sigm(sm*0.25f + mx);
}

// ============ K9: comb = o * (Fh@Fw) + local  -> bf16 ============
__global__ __launch_bounds__(256) void k_comb(const float* __restrict__ o, const float* __restrict__ Fh,
      const float* __restrict__ Fw, const float* __restrict__ local, short* __restrict__ comb){
  const int bc = blockIdx.x;
  __shared__ float fh[128][33];
  __shared__ float fw[32][129];
  const int t = threadIdx.x;
  for (int i = t; i < 4096; i += 256) fh[i>>5][i&31]  = Fh[(size_t)bc*4096 + i];
  for (int i = t; i < 4096; i += 256) fw[i>>7][i&127] = Fw[(size_t)bc*4096 + i];
  __syncthreads();
  for (int i = t; i < 16384; i += 256){
    int y = i >> 7, x = i & 127;
    float g = 0.f;
    #pragma unroll
    for (int kk = 0; kk < 32; ++kk) g += fh[y][kk]*fw[kk][x];
    size_t idx = (size_t)bc*16384 + i;
    comb[idx] = f2bs(o[idx]*g + local[idx]);
  }
}

// ============ K10: reflect-pad + depthwise 8x8 + bn (bf16 input) ============
__global__ __launch_bounds__(256) void k_dw(const short* __restrict__ comb, const float* __restrict__ dw,
      const float* __restrict__ gg, const float* __restrict__ bb, float* __restrict__ out){
  const int bz = blockIdx.y;
  const int oy0 = blockIdx.x*16;
  const int c = bz & 127;
  __shared__ float xs[23][136];
  __shared__ float wsm[64];
  const int t = threadIdx.x;
  if (t < 64) wsm[t] = dw[c*64 + t];
  for (int i = t; i < 23*135; i += 256){
    int py = i / 135, px = i - py*135;
    int gy = oy0 + py - 3, gx = px - 3;
    float v = 0.f;
    if (gy >= 0 && gy <= 128 && gx >= 0 && gx <= 128){
      int yy = (gy==128)?126:gy, xx = (gx==128)?126:gx;
      v = s2f(comb[((size_t)bz*128 + yy)*128 + xx]);
    }
    xs[py][px] = v;
  }
  __syncthreads();
  const int tx = t & 31, ty = t >> 5;
  const int x0 = tx*4, y0 = ty*2;
  float acc[2][4] = {};
  #pragma unroll
  for (int iy = 0; iy < 9; ++iy){
    float row[12];
    *(float4*)&row[0] = *(const float4*)&xs[y0+iy][x0];
    *(float4*)&row[4] = *(const float4*)&xs[y0+iy][x0+4];
    *(float4*)&row[8] = *(const float4*)&xs[y0+iy][x0+8];
    #pragma unroll
    for (int dy = 0; dy < 2; ++dy){
      const int ky = iy - dy;
      if (ky < 0 || ky > 7) continue;
      #pragma unroll
      for (int kx = 0; kx < 8; ++kx){
        float wv = wsm[ky*8 + kx];
        #pragma unroll
        for (int dx = 0; dx < 4; ++dx)
          acc[dy][dx] += wv * row[dx + kx];
      }
    }
  }
  float g = gg[c], bi = bb[c];
  #pragma unroll
  for (int dy = 0; dy < 2; ++dy){
    float4 o4;
    o4.x = acc[dy][0]*g + bi;
    o4.y = acc[dy][1]*g + bi;
    o4.z = acc[dy][2]*g + bi;
    o4.w = acc[dy][3]*g + bi;
    *(float4*)&out[((size_t)bz*128 + oy0 + y0 + dy)*128 + x0] = o4;
  }
}

// ============ P7: zero omT halo cols ============
__global__ void k_omzero(short* __restrict__ omT){
  int t = blockIdx.x*256 + threadIdx.x;
  int ci = t & 127, side = (t >> 7) & 1, row = t >> 8;
  int cpad = side ? 129 : 0;
  omT[((size_t)row*130 + cpad)*128 + ci] = 0;
}

// ============ P8: repack up_w -> wup[tap][co][ci] bf16 ============
__global__ __launch_bounds__(256) void k_uwrep(const float* __restrict__ w, short* __restrict__ wup){
  int i = blockIdx.x*256 + threadIdx.x;
  int ci = i & 127, co = (i >> 7) & 63, tap = i >> 13;
  wup[i] = f2bs(w[(co*128 + ci)*9 + tap]);
}

// ============ P10: proj_pw fp32 -> bf16 [co][ci] ============
__global__ __launch_bounds__(256) void k_wpwrep(const float* __restrict__ w, short* __restrict__ wpw){
  int i = blockIdx.x*256 + threadIdx.x;
  wpw[i] = f2bs(w[i]);
}

// ============ P11: proj1 NCHW fp32 -> p1T [b][pix][ci] bf16 ============
__global__ __launch_bounds__(256) void k_prep(const float* __restrict__ p1, short* __restrict__ p1T){
  const int blk = blockIdx.x;
  const int cgrp = blk & 1, cig = (blk >> 1) & 3, r = (blk >> 3) & 127, b = blk >> 10;
  const int c0 = cgrp*64, ci0 = cig*32;
  __shared__ float lds[32][65];
  const int t = threadIdx.x;
  for (int i = t; i < 2048; i += 256){
    int lci = i >> 6, c = i & 63;
    lds[lci][c] = p1[((size_t)(b*128 + ci0 + lci)*128 + r)*128 + c0 + c];
  }
  __syncthreads();
  for (int i = t; i < 2048; i += 256){
    int lci = i & 31, cc = i >> 5;
    p1T[((size_t)(b*128 + r)*128 + c0 + cc)*128 + ci0 + lci] = f2bs(lds[lci][cc]);
  }
}

// ============ K11: 1x1 proj conv 128->128 MFMA -> omT bf16 NHWC+halo ============
__global__ __launch_bounds__(256) void k_pwm(const short* __restrict__ p1T, const short* __restrict__ wpw,
      short* __restrict__ omT){
  int blk = blockIdx.x;
  blk = (blk & 7)*64 + (blk >> 3);           // XCD swizzle (grid 512)
  const int b = blk >> 7, y = blk & 127;
  const int t = threadIdx.x, lane = t & 63, wave = t >> 6;
  const int quad = lane >> 4, l15 = lane & 15;
  const int m0 = (wave >> 1)*64, n0 = (wave & 1)*64;
  __shared__ __align__(16) short smem[17408];   // as 4096 + bs 4096; epilogue tb[128][136]
  short* as = smem;
  short* bs = smem + 4096;
  const short* xrow = p1T + (size_t)(b*128 + y)*128*128;
  f32x4 acc[4][4];
  #pragma unroll
  for (int i = 0; i < 4; ++i)
    #pragma unroll
    for (int j = 0; j < 4; ++j) acc[i][j] = (f32x4){0.f,0.f,0.f,0.f};
  for (int ch = 0; ch < 4; ++ch){
    const int ci0 = ch*32;
    __syncthreads();
    for (int i = t; i < 512; i += 256){
      int col = i >> 2, cq = i & 3;
      *(uint4*)&as[(col*4 + SLOT(col,cq))*8] = *(const uint4*)&xrow[col*128 + ci0 + cq*8];
    }
    for (int i = t; i < 512; i += 256){
      int rr = i >> 2, cq = i & 3;
      *(uint4*)&bs[(rr*4 + SLOT(rr,cq))*8] = *(const uint4*)&wpw[rr*128 + ci0 + cq*8];
    }
    __syncthreads();
    short8 af[4], bf[4];
    #pragma unroll
    for (int mt = 0; mt < 4; ++mt){
      int row = m0 + mt*16 + l15;
      af[mt] = *(const short8*)&as[(row*4 + SLOT(row,quad))*8];
    }
    #pragma unroll
    for (int nt = 0; nt < 4; ++nt){
      int row = n0 + nt*16 + l15;
      bf[nt] = *(const short8*)&bs[(row*4 + SLOT(row,quad))*8];
    }
    #pragma unroll
    for (int mt = 0; mt < 4; ++mt)
      #pragma unroll
      for (int nt = 0; nt < 4; ++nt)
        acc[mt][nt] = __builtin_amdgcn_mfma_f32_16x16x32_bf16(af[mt], bf[nt], acc[mt][nt], 0, 0, 0);
  }
  // epilogue: transpose to [x][co] in LDS, vectorized omT row writes
  __syncthreads();
  short* tb = smem;   // [128][136]
  #pragma unroll
  for (int nt = 0; nt < 4; ++nt){
    int co = n0 + nt*16 + l15;
    #pragma unroll
    for (int mt = 0; mt < 4; ++mt){
      int xb = m0 + mt*16 + quad*4;
      #pragma unroll
      for (int r = 0; r < 4; ++r)
        tb[(xb + r)*136 + co] = f2bs(acc[mt][nt][r]);
    }
  }
  __syncthreads();
  for (int i = t; i < 2048; i += 256){
    int x = i >> 4, c8 = i & 15;
    *(uint4*)&omT[((size_t)(b*128 + y)*130 + x + 1)*128 + c8*8] = *(const uint4*)&tb[x*136 + c8*8];
  }
}

// ============ K12: transposed 3x3 stride-2 conv 128->64 (MFMA, parity decomp) ============
__global__ __launch_bounds__(256) void k_upm(const short* __restrict__ omT, const short* __restrict__ wup,
      float* __restrict__ out){
  int blk = blockIdx.x;
  blk = (blk & 7)*64 + (blk >> 3);           // XCD swizzle (grid 512)
  const int b = blk >> 7, y = blk & 127;
  const int t = threadIdx.x, lane = t & 63, wave = t >> 6;
  const int quad = lane >> 4, l15 = lane & 15;
  const int m0w = wave*32;
  __shared__ __align__(16) char smem[53504];
  short* asp = (short*)smem;
  short* bsp = (short*)(smem + 16640);
  float* ptile = (float*)smem;
  const int PAR[9] = {3,2,3, 1,0,1, 3,2,3};
  const int ROW[9] = {0,0,0, 0,0,0, 1,1,1};
  const int SHF[9] = {0,0,1, 0,0,1, 0,0,1};
  f32x4 acc[4][2][4];
  #pragma unroll
  for (int p = 0; p < 4; ++p)
    #pragma unroll
    for (int mt = 0; mt < 2; ++mt)
      #pragma unroll
      for (int nt = 0; nt < 4; ++nt) acc[p][mt][nt] = (f32x4){0.f,0.f,0.f,0.f};
  for (int ch = 0; ch < 4; ++ch){
    const int ci0 = ch*32;
    __syncthreads();
    for (int i = t; i < 1040; i += 256){
      int rw = (i >= 520), j = i - rw*520;
      int col = j >> 2, cq = j & 3;
      int row = rw*130 + col;
      uint4 val = {0,0,0,0};
      if (y + rw < 128)
        val = *(const uint4*)&omT[((size_t)(b*128 + y + rw)*130 + col)*128 + ci0 + cq*8];
      *(uint4*)&asp[(row*4 + SLOT(row,cq))*8] = val;
    }
    for (int i = t; i < 2304; i += 256){
      int rr = i >> 2, cq = i & 3;
      *(uint4*)&bsp[(rr*4 + SLOT(rr,cq))*8] = *(const uint4*)&wup[rr*128 + ci0 + cq*8];
    }
    __syncthreads();
    #pragma unroll
    for (int k = 0; k < 9; ++k){
      const int pr = PAR[k], rw = ROW[k], sh = SHF[k];
      if (rw && y == 127) continue;
      short8 af[2], bf[4];
      #pragma unroll
      for (int mt = 0; mt < 2; ++mt){
        int row = rw*130 + m0w + mt*16 + l15 + 1 + sh;
        af[mt] = *(const short8*)&asp[(row*4 + SLOT(row,quad))*8];
      }
      #pragma unroll
      for (int nt = 0; nt < 4; ++nt){
        int row = k*64 + nt*16 + l15;
        bf[nt] = *(const short8*)&bsp[(row*4 + SLOT(row,quad))*8];
      }
      #pragma unroll
      for (int mt = 0; mt < 2; ++mt)
        #pragma unroll
        for (int nt = 0; nt < 4; ++nt)
          acc[pr][mt][nt] = __builtin_amdgcn_mfma_f32_16x16x32_bf16(af[mt], bf[nt], acc[pr][mt][nt], 0, 0, 0);
    }
  }
  #pragma unroll
  for (int p = 0; p < 4; ++p){
    __syncthreads();
    #pragma unroll
    for (int mt = 0; mt < 2; ++mt)
      #pragma unroll
      for (int nt = 0; nt < 4; ++nt){
        int co = nt*16 + l15;
        int xb = m0w + mt*16 + quad*4;
        #pragma unroll
        for (int r = 0; r < 4; ++r)
          ptile[co*132 + xb + r] = acc[p][mt][nt][r];
      }
    __syncthreads();
    int py = p >> 1, px = p & 1;
    int Y = 2*y + py;
    for (int i = t; i < 8192; i += 256){
      int co = i >> 7, xx = i & 127;
      out[((size_t)(b*64 + co)*256 + Y)*256 + 2*xx + px] = ptile[co*132 + xx];
    }
  }
}

extern "C" void kernel_launch(void* const* d_in, const int* in_sizes, int n_in,
                              void* d_out, int out_size, void* d_ws, size_t ws_size,
                              hipStream_t stream) {
  const float* x       = (const float*)d_in[0];
  const float* conv_w  = (const float*)d_in[1];
  const float* bn1_g   = (const float*)d_in[2];
  const float* bn1_b   = (const float*)d_in[3];
  const float* qkv_w   = (const float*)d_in[4];
  const float* loc1_w  = (const float*)d_in[5];
  const float* loc1_g  = (const float*)d_in[6];
  const float* loc1_b  = (const float*)d_in[7];
  const float* loc2_w  = (const float*)d_in[8];
  const float* loc2_g  = (const float*)d_in[9];
  const float* loc2_b  = (const float*)d_in[10];
  const float* rel_t   = (const float*)d_in[11];
  const float* cw_w    = (const float*)d_in[12];
  const float* cw_g    = (const float*)d_in[13];
  const float* cw_b    = (const float*)d_in[14];
  const float* hc_w    = (const float*)d_in[15];
  const float* hc_g    = (const float*)d_in[16];
  const float* hc_b    = (const float*)d_in[17];
  const float* hw_w    = (const float*)d_in[18];
  const float* hw_g    = (const float*)d_in[19];
  const float* hw_b    = (const float*)d_in[20];
  const float* proj_dw = (const float*)d_in[21];
  const float* proj_g  = (const float*)d_in[22];
  const float* proj_b  = (const float*)d_in[23];
  const float* proj_pw = (const float*)d_in[24];
  const float* up_w    = (const float*)d_in[25];

  char* ws = (char*)d_ws;
  float* local  = (float*)(ws + OFF_LOCAL);
  bf16*  q      = (bf16*)(ws + OFF_Q);
  bf16*  k      = (bf16*)(ws + OFF_K);
  bf16*  v      = (bf16*)(ws + OFF_V);
  bf16*  dots   = (bf16*)(ws + OFF_DOTS);
  bf16*  z1     = (bf16*)(ws + OFF_Z1);
  bf16*  z2     = (bf16*)(ws + OFF_Z2);
  bf16*  z3     = (bf16*)(ws + OFF_Z3);
  float* G1     = (float*)(ws + OFF_G1);
  float* G2     = (float*)(ws + OFF_G2);
  float* G3     = (float*)(ws + OFF_G3);
  short* xT     = (short*)(ws + OFF_DOTS);
  short* hT     = (short*)(ws + OFF_HT);
  short* w2bf   = (short*)(ws + OFF_Z1);
  short* wloc   = (short*)(ws + OFF_Z2);
  short* wqkv   = (short*)(ws + OFF_Z3);
  short* omT    = (short*)(ws + OFF_DOTS);
  short* wup    = (short*)(ws + OFF_Z1);
  short* wpw    = (short*)(ws + OFF_Z2);
  short* p1T    = (short*)(ws + OFF_K);
  float* o_img  = (float*)(ws + OFF_Q);
  float* Fh     = (float*)(ws + OFF_DOTS);
  float* Fw     = (float*)(ws + OFF_DOTS + 8388608);
  short* combB  = (short*)(ws + OFF_H);
  float* proj1  = (float*)(ws + OFF_LOCAL);
  float* outp   = (float*)d_out;

  k_wrep <<<1152, 256, 0, stream>>>(conv_w, w2bf);
  k_xzero<<<1024, 256, 0, stream>>>(xT);
  k_xrep <<<8192, 256, 0, stream>>>(x, xT);
  k_hzero<<<512, 256, 0, stream>>>(hT);
  k_conv1m<<<1024, 256, 0, stream>>>(xT, w2bf, bn1_g, bn1_b, hT);
  k_lwrep<<<576, 256, 0, stream>>>(loc1_w, loc1_g, loc2_w, loc2_g, wloc);
  k_localm<<<1024, 256, 0, stream>>>(hT, wloc, loc1_b, loc2_b, local);
  k_wqkvrep<<<192, 256, 0, stream>>>(qkv_w, wqkv);
  k_qkvm <<<dim3(512,3), 256, 0, stream>>>(hT, wqkv, q, k, v);
  k_dots <<<dim3(NWIN,8), 256, 0, stream>>>(q, k, rel_t, dots);
  k_zall <<<NWIN, 256, 0, stream>>>(dots, z1, z2, z3);
  k_gate <<<dim3(NWIN,2),  256, 0, stream>>>(z1, cw_w, cw_g, cw_b, G1, 8, 64);
  k_gate <<<dim3(NWIN,2),  256, 0, stream>>>(z2, hc_w, hc_g, hc_b, G2, 64, 8);
  k_gate3<<<NWIN, 256, 0, stream>>>(z3, hw_w, hw_g, hw_b, G3);
  k_attn <<<dim3(NWIN,8), 256, 0, stream>>>(dots, G1, G2, G3, v, o_img);
  k_fw   <<<8192, 256, 0, stream>>>(o_img, Fw);
  k_fh   <<<8192, 256, 0, stream>>>(o_img, Fh);
  k_comb <<<512, 256, 0, stream>>>(o_img, Fh, Fw, local, combB);
  k_dw   <<<dim3(8, BB*128), 256, 0, stream>>>(combB, proj_dw, proj_g, proj_b, proj1);
  k_omzero<<<512, 256, 0, stream>>>(omT);
  k_uwrep<<<288, 256, 0, stream>>>(up_w, wup);
  k_wpwrep<<<64, 256, 0, stream>>>(proj_pw, wpw);
  k_prep <<<4096, 256, 0, stream>>>(proj1, p1T);
  k_pwm  <<<512, 256, 0, stream>>>(p1T, wpw, omT);
  k_upm  <<<512, 256, 0, stream>>>(omT, wup, outp);
}